// Round 1
// baseline (2465.969 us; speedup 1.0000x reference)
//
#include <hip/hip_runtime.h>
#include <hip/hip_bf16.h>

typedef short short8 __attribute__((ext_vector_type(8)));
typedef float f32x4 __attribute__((ext_vector_type(4)));

static __device__ __forceinline__ short f2bf(float f){
  __hip_bfloat16 h = __float2bfloat16(f);
  return __builtin_bit_cast(short, h);
}
static __device__ __forceinline__ float lrelu(float x){ return x > 0.f ? x : 0.2f*x; }
static __device__ __forceinline__ float elu(float x){ return x > 0.f ? x : (__expf(x)-1.f); }

// ------------------------------ GEMM (bf16 MFMA, f32 in/out) ------------------------------
// C[M,N] = A[M,K] @ B[K,N] (+bias). A row-major lda=K, B row-major ldb=N, C ldc given.
template<int BM, int BN, int WR, int WC, bool VEC8>
__global__ __launch_bounds__(256) void gemm_bf16(
    const float* __restrict__ A, const float* __restrict__ B,
    float* __restrict__ C, const float* __restrict__ bias,
    int M, int N, int K, int ldc)
{
  constexpr int BK = 32;
  constexpr int LDA = BK + 8;            // pad to 40 shorts (80B, 16B-aligned rows, spread banks)
  constexpr int WM = BM / WR, WN = BN / WC;
  constexpr int FM = WM / 16, FN = WN / 16;
  __shared__ short Al[BM][LDA];
  __shared__ short Bl[BN][LDA];          // B stored transposed: Bl[n][k]

  const int tid  = threadIdx.x;
  const int wid  = tid >> 6, lane = tid & 63;
  const int wm   = wid / WC, wn = wid % WC;
  const int bm   = blockIdx.x * BM, bn = blockIdx.y * BN;
  const int lr   = lane & 15, lg = lane >> 4;

  f32x4 acc[FM][FN] = {};

  for (int k0 = 0; k0 < K; k0 += BK) {
    __syncthreads();
    // stage A: each chunk = 8 consecutive k of one row
    for (int ch = tid; ch < BM*4; ch += 256) {
      int r = ch >> 2, kc = (ch & 3) * 8;
      int grow = bm + r, gk = k0 + kc;
      short8 v;
      if ((grow < M) && (VEC8 ? (gk + 8 <= K) : false)) {
        const float* ap = A + (size_t)grow*K + gk;
        float4 f0 = *(const float4*)ap;
        float4 f1 = *(const float4*)(ap+4);
        v[0]=f2bf(f0.x); v[1]=f2bf(f0.y); v[2]=f2bf(f0.z); v[3]=f2bf(f0.w);
        v[4]=f2bf(f1.x); v[5]=f2bf(f1.y); v[6]=f2bf(f1.z); v[7]=f2bf(f1.w);
      } else {
        const float* ap = A + (size_t)grow*K + gk;
        #pragma unroll
        for (int j=0;j<8;j++)
          v[j] = (grow < M && gk + j < K) ? f2bf(ap[j]) : (short)0;
      }
      *(short8*)&Al[r][kc] = v;
    }
    // stage B transposed (strided reads; B is small & L2-resident)
    for (int ch = tid; ch < BN*4; ch += 256) {
      int c = ch >> 2, kc = (ch & 3) * 8;
      int gcol = bn + c;
      short8 v;
      #pragma unroll
      for (int j=0;j<8;j++) {
        int gk = k0 + kc + j;
        v[j] = (gcol < N && gk < K) ? f2bf(B[(size_t)gk*N + gcol]) : (short)0;
      }
      *(short8*)&Bl[c][kc] = v;
    }
    __syncthreads();
    short8 af[FM], bfr[FN];
    #pragma unroll
    for (int m=0;m<FM;m++) af[m]  = *(short8*)&Al[wm*WM + m*16 + lr][lg*8];
    #pragma unroll
    for (int n=0;n<FN;n++) bfr[n] = *(short8*)&Bl[wn*WN + n*16 + lr][lg*8];
    #pragma unroll
    for (int m=0;m<FM;m++)
      #pragma unroll
      for (int n=0;n<FN;n++)
        acc[m][n] = __builtin_amdgcn_mfma_f32_16x16x32_bf16(af[m], bfr[n], acc[m][n], 0, 0, 0);
  }
  // epilogue: D layout col=lane&15, row=(lane>>4)*4+q
  #pragma unroll
  for (int m=0;m<FM;m++)
    #pragma unroll
    for (int n=0;n<FN;n++)
      #pragma unroll
      for (int q=0;q<4;q++){
        int row = bm + wm*WM + m*16 + lg*4 + q;
        int col = bn + wn*WN + n*16 + lr;
        if (row < M && col < N){
          float v = acc[m][n][q];
          if (bias) v += bias[col];
          C[(size_t)row*ldc + col] = v;
        }
      }
}

// ------------------------------ BatchNorm (batch stats) + ELU ------------------------------
template<int C>
__global__ __launch_bounds__(256) void colstats(const float* __restrict__ H, int M,
                                                float* __restrict__ ssum, float* __restrict__ ssq){
  constexpr int RG = 256 / C;
  int col = threadIdx.x % C;
  int r0  = blockIdx.x * RG + threadIdx.x / C;
  int stride = gridDim.x * RG;
  float s = 0.f, q = 0.f;
  for (int r = r0; r < M; r += stride){
    float v = H[(size_t)r*C + col];
    s += v; q += v*v;
  }
  atomicAdd(&ssum[col], s);
  atomicAdd(&ssq[col],  q);
}

__global__ void bn_finalize(const float* __restrict__ ssum, const float* __restrict__ ssq,
                            const float* __restrict__ g, const float* __restrict__ bt,
                            float* __restrict__ scale, float* __restrict__ shift, int C, float invM){
  int c = blockIdx.x*blockDim.x + threadIdx.x;
  if (c >= C) return;
  float m  = ssum[c]*invM;
  float var = ssq[c]*invM - m*m;
  float sc = g[c] * rsqrtf(var + 1e-5f);
  scale[c] = sc;
  shift[c] = bt[c] - m*sc;
}

template<int C>
__global__ __launch_bounds__(256) void bn_elu_apply(float* __restrict__ H, int total4,
                                                    const float* __restrict__ sc, const float* __restrict__ sh){
  int i = blockIdx.x*256 + threadIdx.x;
  int stride = gridDim.x*256;
  for (; i < total4; i += stride){
    float4 v = ((const float4*)H)[i];
    int cb = (i*4) & (C-1);
    v.x = elu(v.x*sc[cb+0]+sh[cb+0]);
    v.y = elu(v.y*sc[cb+1]+sh[cb+1]);
    v.z = elu(v.z*sc[cb+2]+sh[cb+2]);
    v.w = elu(v.w*sc[cb+3]+sh[cb+3]);
    ((float4*)H)[i] = v;
  }
}

// ------------------------------ CSR build ------------------------------
__global__ void hist_kernel(const int* __restrict__ d, int E, int* __restrict__ deg){
  int i = blockIdx.x*256 + threadIdx.x;
  if (i < E) atomicAdd(&deg[d[i]], 1);
}

__global__ __launch_bounds__(1024) void scan_kernel(const int* __restrict__ deg, int* __restrict__ offs,
                                                    int* __restrict__ cursor, int n){
  __shared__ int sm[1024];
  __shared__ int carry;
  if (threadIdx.x == 0) carry = 0;
  __syncthreads();
  for (int base = 0; base < n; base += 1024){
    int i = base + threadIdx.x;
    int v = (i < n) ? deg[i] : 0;
    sm[threadIdx.x] = v;
    __syncthreads();
    for (int d = 1; d < 1024; d <<= 1){
      int t = (threadIdx.x >= d) ? sm[threadIdx.x - d] : 0;
      __syncthreads();
      sm[threadIdx.x] += t;
      __syncthreads();
    }
    int excl = sm[threadIdx.x] - v + carry;
    if (i < n){ offs[i] = excl; cursor[i] = excl; }
    __syncthreads();
    if (threadIdx.x == 0) carry += sm[1023];
    __syncthreads();
  }
  if (threadIdx.x == 0) offs[n] = carry;
}

__global__ void scatter_kernel(const int* __restrict__ s, const int* __restrict__ d, int E,
                               int* __restrict__ cursor, int* __restrict__ csr){
  int i = blockIdx.x*256 + threadIdx.x;
  if (i < E){ int pos = atomicAdd(&cursor[d[i]], 1); csr[pos] = s[i]; }
}

// ------------------------------ GAT1 (3 heads x 64) ------------------------------
__global__ __launch_bounds__(256) void gat1_scores(const float* __restrict__ hh,
    const float* __restrict__ as, const float* __restrict__ ad,
    float* __restrict__ ss, float* __restrict__ sd, int n){
  int w = threadIdx.x >> 6, lane = threadIdx.x & 63;
  int row = blockIdx.x*4 + w;
  if (row >= n) return;
  const float* hr = hh + (size_t)row*192;
  float ps[3], pd[3];
  #pragma unroll
  for (int h=0; h<3; h++){
    float v = hr[h*64 + lane];
    ps[h] = v * as[h*64+lane];
    pd[h] = v * ad[h*64+lane];
  }
  #pragma unroll
  for (int m=32; m; m>>=1){
    #pragma unroll
    for (int h=0;h<3;h++){ ps[h] += __shfl_xor(ps[h], m); pd[h] += __shfl_xor(pd[h], m); }
  }
  if (lane == 0){
    #pragma unroll
    for (int h=0;h<3;h++){ ss[row*3+h]=ps[h]; sd[row*3+h]=pd[h]; }
  }
}

// wave per dst: out[dst, h*64+lane] = relu( (Σ_e p_e,h * hh[src_e, h*64+lane]) / Σ_e p_e,h + b )
__global__ __launch_bounds__(256) void gat1_gather(const int* __restrict__ offs, const int* __restrict__ csr,
    const float* __restrict__ hh, const float* __restrict__ ss, const float* __restrict__ sd,
    const float* __restrict__ bias, float* __restrict__ out, int n){
  int w = threadIdx.x >> 6, lane = threadIdx.x & 63;
  int dst = blockIdx.x*4 + w;
  if (dst >= n) return;
  float sd0 = sd[dst*3+0], sd1 = sd[dst*3+1], sd2 = sd[dst*3+2];
  // self-loop
  float p0 = __expf(lrelu(ss[dst*3+0]+sd0));
  float p1 = __expf(lrelu(ss[dst*3+1]+sd1));
  float p2 = __expf(lrelu(ss[dst*3+2]+sd2));
  const float* hr = hh + (size_t)dst*192;
  float a0 = p0*hr[lane], a1 = p1*hr[64+lane], a2 = p2*hr[128+lane];
  float d0 = p0, d1 = p1, d2 = p2;
  int pe = offs[dst+1];
  for (int p = offs[dst]; p < pe; ++p){
    int src = csr[p];
    float q0 = __expf(lrelu(ss[src*3+0]+sd0));
    float q1 = __expf(lrelu(ss[src*3+1]+sd1));
    float q2 = __expf(lrelu(ss[src*3+2]+sd2));
    const float* sr = hh + (size_t)src*192;
    a0 += q0*sr[lane]; a1 += q1*sr[64+lane]; a2 += q2*sr[128+lane];
    d0 += q0; d1 += q1; d2 += q2;
  }
  float v0 = a0/d0 + bias[lane];
  float v1 = a1/d1 + bias[64+lane];
  float v2 = a2/d2 + bias[128+lane];
  float* orow = out + (size_t)dst*192;
  orow[lane]      = v0 > 0.f ? v0 : 0.f;
  orow[64+lane]   = v1 > 0.f ? v1 : 0.f;
  orow[128+lane]  = v2 > 0.f ? v2 : 0.f;
}

// ------------------------------ GAT2/GAT3 (1 head x 30), fused ------------------------------
__global__ __launch_bounds__(256) void gat23_scores(const float* __restrict__ h2, const float* __restrict__ h3v,
    const float* __restrict__ a2s, const float* __restrict__ a2d,
    const float* __restrict__ a3s, const float* __restrict__ a3d,
    float* __restrict__ s2s, float* __restrict__ s2d, float* __restrict__ s3s, float* __restrict__ s3d, int n){
  int w = threadIdx.x >> 6, lane = threadIdx.x & 63;
  int row = blockIdx.x*4 + w;
  if (row >= n) return;
  float p[4] = {0.f,0.f,0.f,0.f};
  if (lane < 30){
    float v2 = h2[(size_t)row*30+lane], v3 = h3v[(size_t)row*30+lane];
    p[0]=v2*a2s[lane]; p[1]=v2*a2d[lane]; p[2]=v3*a3s[lane]; p[3]=v3*a3d[lane];
  }
  #pragma unroll
  for (int m=32; m; m>>=1){
    #pragma unroll
    for (int j=0;j<4;j++) p[j] += __shfl_xor(p[j], m);
  }
  if (lane == 0){ s2s[row]=p[0]; s2d[row]=p[1]; s3s[row]=p[2]; s3d[row]=p[3]; }
}

__global__ __launch_bounds__(256) void gat23_gather(const int* __restrict__ offs, const int* __restrict__ csr,
    const float* __restrict__ hh2, const float* __restrict__ hh3,
    const float* __restrict__ s2s, const float* __restrict__ s2d,
    const float* __restrict__ s3s, const float* __restrict__ s3d,
    const float* __restrict__ b2, const float* __restrict__ b3,
    float* __restrict__ zs, float* __restrict__ mus, float* __restrict__ lvs, int n){
  int w = threadIdx.x >> 6, lane = threadIdx.x & 63;
  int dst = blockIdx.x*4 + w;
  if (dst >= n) return;
  bool lo = lane < 32;
  int c = lo ? lane : lane - 32;
  float sdA = s2d[dst], sdB = s3d[dst];
  float p2 = __expf(lrelu(s2s[dst]+sdA));
  float p3 = __expf(lrelu(s3s[dst]+sdB));
  float val = 0.f;
  if (c < 30) val = lo ? hh2[(size_t)dst*30+c] : hh3[(size_t)dst*30+c];
  float acc = (lo ? p2 : p3) * val;
  float den2 = p2, den3 = p3;
  int pe = offs[dst+1];
  for (int p = offs[dst]; p < pe; ++p){
    int src = csr[p];
    float q2 = __expf(lrelu(s2s[src]+sdA));
    float q3 = __expf(lrelu(s3s[src]+sdB));
    float v = 0.f;
    if (c < 30) v = lo ? hh2[(size_t)src*30+c] : hh3[(size_t)src*30+c];
    acc += (lo ? q2 : q3) * v;
    den2 += q2; den3 += q3;
  }
  if (c < 30){
    if (lo){
      float v = acc/den2 + b2[c];
      zs[(size_t)dst*30+c]  = v;
      mus[(size_t)dst*30+c] = v;
    } else {
      lvs[(size_t)dst*30+c] = acc/den3 + b3[c];
    }
  }
}

// ------------------------------ row softmax over 10 ------------------------------
__global__ __launch_bounds__(256) void softmax10(const float* __restrict__ in, float* __restrict__ out, int n){
  int row = blockIdx.x*256 + threadIdx.x;
  if (row >= n) return;
  const float* r = in + (size_t)row*10;
  float m = r[0];
  #pragma unroll
  for (int j=1;j<10;j++) m = fmaxf(m, r[j]);
  float e[10], s = 0.f;
  #pragma unroll
  for (int j=0;j<10;j++){ e[j] = __expf(r[j]-m); s += e[j]; }
  float inv = 1.f/s;
  float* o = out + (size_t)row*10;
  #pragma unroll
  for (int j=0;j<10;j++) o[j] = e[j]*inv;
}

// ------------------------------ host ------------------------------
static inline int cdiv(int a, int b){ return (a + b - 1) / b; }

extern "C" void kernel_launch(void* const* d_in, const int* in_sizes, int n_in,
                              void* d_out, int out_size, void* d_ws, size_t ws_size,
                              hipStream_t stream)
{
  const float* x        = (const float*)d_in[0];
  const int*   ei       = (const int*)  d_in[1];
  const float* enc_w1   = (const float*)d_in[2];
  const float* enc_g1   = (const float*)d_in[4];
  const float* enc_bt1  = (const float*)d_in[5];
  const float* enc_w2   = (const float*)d_in[6];
  const float* enc_g2   = (const float*)d_in[8];
  const float* enc_bt2  = (const float*)d_in[9];
  const float* gat1_w   = (const float*)d_in[10];
  const float* gat1_as  = (const float*)d_in[11];
  const float* gat1_ad  = (const float*)d_in[12];
  const float* gat1_b   = (const float*)d_in[13];
  const float* gat2_w   = (const float*)d_in[14];
  const float* gat2_as  = (const float*)d_in[15];
  const float* gat2_ad  = (const float*)d_in[16];
  const float* gat2_b   = (const float*)d_in[17];
  const float* gat3_w   = (const float*)d_in[18];
  const float* gat3_as  = (const float*)d_in[19];
  const float* gat3_ad  = (const float*)d_in[20];
  const float* gat3_b   = (const float*)d_in[21];
  const float* dec_w1   = (const float*)d_in[22];
  const float* dec_g1   = (const float*)d_in[24];
  const float* dec_bt1  = (const float*)d_in[25];
  const float* dec_w2   = (const float*)d_in[26];
  const float* dec_g2   = (const float*)d_in[28];
  const float* dec_bt2  = (const float*)d_in[29];
  const float* dec_w3   = (const float*)d_in[30];
  const float* dec_b3   = (const float*)d_in[31];
  const float* clu_w1   = (const float*)d_in[32];
  const float* clu_g1   = (const float*)d_in[34];
  const float* clu_bt1  = (const float*)d_in[35];
  const float* clu_w2   = (const float*)d_in[36];
  const float* clu_b2   = (const float*)d_in[37];

  const int N = in_sizes[0] / 1000;
  const int E = in_sizes[1] / 2;
  const int* e_src = ei;
  const int* e_dst = ei + E;

  float* out  = (float*)d_out;
  float* pred = out;
  float* xrec = out + (size_t)N*10;
  float* zs   = xrec + (size_t)N*1000;
  float* mus  = zs  + (size_t)N*30;
  float* lvs  = mus + (size_t)N*30;

  char* ws = (char*)d_ws;
  size_t off = 0;
  auto alloc = [&](size_t bytes)->char*{
    char* p = ws + off;
    off = (off + bytes + 255) & ~(size_t)255;
    return p;
  };
  float* h1    = (float*)alloc((size_t)N*256*4);   // reused as d2
  float* h2    = (float*)alloc((size_t)N*128*4);   // reused as d1
  float* hh1   = (float*)alloc((size_t)N*192*4);   // reused as c1
  float* h3    = (float*)alloc((size_t)N*192*4);
  float* hh2   = (float*)alloc((size_t)N*30*4);
  float* hh3   = (float*)alloc((size_t)N*30*4);
  float* ss1   = (float*)alloc((size_t)N*3*4);
  float* sd1   = (float*)alloc((size_t)N*3*4);
  float* s2s   = (float*)alloc((size_t)N*4);
  float* s2d   = (float*)alloc((size_t)N*4);
  float* s3s   = (float*)alloc((size_t)N*4);
  float* s3d   = (float*)alloc((size_t)N*4);
  float* c2    = (float*)alloc((size_t)N*10*4);
  float* stats = (float*)alloc(1024*4);
  int*   deg   = (int*)alloc((size_t)(N+1)*4);
  int*   offs  = (int*)alloc((size_t)(N+1)*4);
  int*   cursor= (int*)alloc((size_t)(N+1)*4);
  int*   csr   = (int*)alloc((size_t)E*4);
  float* d1 = h2; float* d2 = h1; float* c1 = hh1;
  float* ssum = stats, *ssq = stats+256, *scale = stats+512, *shift = stats+768;

  // --- CSR build (dst-sorted adjacency) ---
  hipMemsetAsync(deg, 0, (size_t)(N+1)*4, stream);
  hist_kernel<<<cdiv(E,256), 256, 0, stream>>>(e_dst, E, deg);
  scan_kernel<<<1, 1024, 0, stream>>>(deg, offs, cursor, N);
  scatter_kernel<<<cdiv(E,256), 256, 0, stream>>>(e_src, e_dst, E, cursor, csr);

  auto bn256 = [&](float* H, const float* g, const float* bt){
    hipMemsetAsync(stats, 0, 512*4, stream);
    colstats<256><<<256, 256, 0, stream>>>(H, N, ssum, ssq);
    bn_finalize<<<1, 256, 0, stream>>>(ssum, ssq, g, bt, scale, shift, 256, 1.f/(float)N);
    bn_elu_apply<256><<<2048, 256, 0, stream>>>(H, N*256/4, scale, shift);
  };
  auto bn128 = [&](float* H, const float* g, const float* bt){
    hipMemsetAsync(stats, 0, 512*4, stream);
    colstats<128><<<256, 256, 0, stream>>>(H, N, ssum, ssq);
    bn_finalize<<<1, 128, 0, stream>>>(ssum, ssq, g, bt, scale, shift, 128, 1.f/(float)N);
    bn_elu_apply<128><<<2048, 256, 0, stream>>>(H, N*128/4, scale, shift);
  };

  // --- encoder ---
  gemm_bf16<64,256,1,4,true><<<dim3(cdiv(N,64),1), 256, 0, stream>>>(x, enc_w1, h1, nullptr, N, 256, 1000, 256);
  bn256(h1, enc_g1, enc_bt1);
  gemm_bf16<128,128,2,2,true><<<dim3(cdiv(N,128),1), 256, 0, stream>>>(h1, enc_w2, h2, nullptr, N, 128, 256, 128);
  bn128(h2, enc_g2, enc_bt2);

  // --- GAT1 ---
  gemm_bf16<128,64,2,2,true><<<dim3(cdiv(N,128),3), 256, 0, stream>>>(h2, gat1_w, hh1, nullptr, N, 192, 128, 192);
  gat1_scores<<<cdiv(N,4), 256, 0, stream>>>(hh1, gat1_as, gat1_ad, ss1, sd1, N);
  gat1_gather<<<cdiv(N,4), 256, 0, stream>>>(offs, csr, hh1, ss1, sd1, gat1_b, h3, N);

  // --- GAT2 (mu) / GAT3 (logvar) ---
  gemm_bf16<128,32,4,1,true><<<dim3(cdiv(N,128),1), 256, 0, stream>>>(h3, gat2_w, hh2, nullptr, N, 30, 192, 30);
  gemm_bf16<128,32,4,1,true><<<dim3(cdiv(N,128),1), 256, 0, stream>>>(h3, gat3_w, hh3, nullptr, N, 30, 192, 30);
  gat23_scores<<<cdiv(N,4), 256, 0, stream>>>(hh2, hh3, gat2_as, gat2_ad, gat3_as, gat3_ad, s2s, s2d, s3s, s3d, N);
  gat23_gather<<<cdiv(N,4), 256, 0, stream>>>(offs, csr, hh2, hh3, s2s, s2d, s3s, s3d, gat2_b, gat3_b, zs, mus, lvs, N);

  // --- decoder ---
  gemm_bf16<128,128,2,2,false><<<dim3(cdiv(N,128),1), 256, 0, stream>>>(zs, dec_w1, d1, nullptr, N, 128, 30, 128);
  bn128(d1, dec_g1, dec_bt1);
  gemm_bf16<64,256,1,4,true><<<dim3(cdiv(N,64),1), 256, 0, stream>>>(d1, dec_w2, d2, nullptr, N, 256, 128, 256);
  bn256(d2, dec_g2, dec_bt2);
  gemm_bf16<64,256,1,4,true><<<dim3(cdiv(N,64),4), 256, 0, stream>>>(d2, dec_w3, xrec, dec_b3, N, 1000, 256, 1000);

  // --- cluster head ---
  gemm_bf16<128,128,2,2,false><<<dim3(cdiv(N,128),1), 256, 0, stream>>>(zs, clu_w1, c1, nullptr, N, 128, 30, 128);
  bn128(c1, clu_g1, clu_bt1);
  gemm_bf16<128,32,4,1,true><<<dim3(cdiv(N,128),1), 256, 0, stream>>>(c1, clu_w2, c2, clu_b2, N, 10, 128, 10);
  softmax10<<<cdiv(N,256), 256, 0, stream>>>(c2, pred, N);
}

// Round 2
// 1031.984 us; speedup vs baseline: 2.3895x; 2.3895x over previous
//
#include <hip/hip_runtime.h>
#include <hip/hip_bf16.h>

typedef short short8 __attribute__((ext_vector_type(8)));
typedef short short4v __attribute__((ext_vector_type(4)));
typedef float f32x4 __attribute__((ext_vector_type(4)));

static __device__ __forceinline__ short f2bf(float f){
  __hip_bfloat16 h = __float2bfloat16(f);
  return __builtin_bit_cast(short, h);
}
static __device__ __forceinline__ float b2f(short s){
  unsigned int u = ((unsigned int)(unsigned short)s) << 16;
  return __builtin_bit_cast(float, u);
}
static __device__ __forceinline__ float lrelu(float x){ return x > 0.f ? x : 0.2f*x; }
static __device__ __forceinline__ float eluf(float x){ return x > 0.f ? x : (__expf(x)-1.f); }

// ============================ GEMM: bf16 MFMA, reg-staged dbuf LDS ============================
// C[M,N] = A[M,K] @ B^T[N,K]^T. A: bf16 [M][K] (or f32 if AF32). Bt: bf16 [N][K].
// BM=128 fixed, 256 thr (4 waves, 2x2), swizzled LDS granules, 1 barrier per k-step.
template<int BN, int BK, bool AF32, bool OBF16>
__global__ __launch_bounds__(256) void gemm2(
    const void* __restrict__ Av, const short* __restrict__ Bt,
    void* __restrict__ Cv, const float* __restrict__ bias,
    int M, int N, int K, int ldc)
{
  constexpr int BM = 128;
  constexpr int GPR = BK/8;           // 16B granules per row
  constexpr int WM = 64, WN = BN/2;   // 2x2 waves
  constexpr int FM = 4, FN = WN/16;
  constexpr int NKK = BK/32;
  constexpr int AG = (BM*GPR)/256;
  constexpr int BG = (BN*GPR)/256;
  __shared__ short lds[2][(BM+BN)*BK];

  const int tid = threadIdx.x, wid = tid>>6, lane = tid&63;
  const int wm = wid>>1, wn = wid&1;
  const int bm = blockIdx.x*BM, bn = blockIdx.y*BN;
  const int lr = lane&15, lg = lane>>4;
  const float* A32 = (const float*)Av;
  const short* A16 = (const short*)Av;

  f32x4 acc[FM][FN] = {};
  const int nt = (K + BK - 1)/BK;

  short8 ra[AG], rb[BG];
  int arow[AG], acol[AG], brow[BG], bcol[BG];
  #pragma unroll
  for (int p=0;p<AG;p++){ int idx=p*256+tid; arow[p]=idx/GPR; acol[p]=(idx%GPR)*8; }
  #pragma unroll
  for (int p=0;p<BG;p++){ int idx=p*256+tid; brow[p]=idx/GPR; bcol[p]=(idx%GPR)*8; }

  auto LOADT = [&](int t){
    int k0 = t*BK;
    #pragma unroll
    for (int p=0;p<AG;p++){
      int r = bm + arow[p], k = k0 + acol[p];
      short8 v = {};
      if (r < M && k + 8 <= K){
        if (AF32){
          const float* ap = A32 + (size_t)r*K + k;
          float4 f0 = *(const float4*)ap, f1 = *(const float4*)(ap+4);
          v[0]=f2bf(f0.x); v[1]=f2bf(f0.y); v[2]=f2bf(f0.z); v[3]=f2bf(f0.w);
          v[4]=f2bf(f1.x); v[5]=f2bf(f1.y); v[6]=f2bf(f1.z); v[7]=f2bf(f1.w);
        } else {
          v = *(const short8*)(A16 + (size_t)r*K + k);
        }
      }
      ra[p] = v;
    }
    #pragma unroll
    for (int p=0;p<BG;p++){
      int rn = bn + brow[p], k = k0 + bcol[p];
      short8 v = {};
      if (rn < N && k + 8 <= K) v = *(const short8*)(Bt + (size_t)rn*K + k);
      rb[p] = v;
    }
  };
  auto STORET = [&](int buf){
    #pragma unroll
    for (int p=0;p<AG;p++){
      int g = acol[p]>>3;
      *(short8*)&lds[buf][arow[p]*BK + ((g ^ (arow[p]&(GPR-1)))<<3)] = ra[p];
    }
    #pragma unroll
    for (int p=0;p<BG;p++){
      int g = bcol[p]>>3;
      *(short8*)&lds[buf][(BM + brow[p])*BK + ((g ^ (brow[p]&(GPR-1)))<<3)] = rb[p];
    }
  };

  LOADT(0);
  STORET(0);
  __syncthreads();
  int cur = 0;
  for (int t = 0; t < nt; ++t){
    if (t+1 < nt) LOADT(t+1);          // issue next tile early: latency hides under MFMA
    #pragma unroll
    for (int kk=0; kk<NKK; kk++){
      short8 af[FM], bfm[FN];
      #pragma unroll
      for (int m=0;m<FM;m++){
        int row = wm*WM + m*16 + lr;
        af[m] = *(short8*)&lds[cur][row*BK + (((kk*4+lg) ^ (row&(GPR-1)))<<3)];
      }
      #pragma unroll
      for (int n=0;n<FN;n++){
        int row = wn*WN + n*16 + lr;
        bfm[n] = *(short8*)&lds[cur][(BM+row)*BK + (((kk*4+lg) ^ (row&(GPR-1)))<<3)];
      }
      #pragma unroll
      for (int m=0;m<FM;m++)
        #pragma unroll
        for (int n=0;n<FN;n++)
          acc[m][n] = __builtin_amdgcn_mfma_f32_16x16x32_bf16(af[m], bfm[n], acc[m][n], 0, 0, 0);
    }
    if (t+1 < nt) STORET(cur^1);       // write next tile into the other buffer
    __syncthreads();
    cur ^= 1;
  }

  #pragma unroll
  for (int m=0;m<FM;m++)
    #pragma unroll
    for (int n=0;n<FN;n++)
      #pragma unroll
      for (int q=0;q<4;q++){
        int row = bm + wm*WM + m*16 + lg*4 + q;
        int col = bn + wn*WN + n*16 + lr;
        if (row < M && col < N){
          float v = acc[m][n][q];
          if (bias) v += bias[col];
          if (OBF16) ((short*)Cv)[(size_t)row*ldc + col] = f2bf(v);
          else       ((float*)Cv)[(size_t)row*ldc + col] = v;
        }
      }
}

// ============================ weight transpose/convert: B[K][N] f32 -> Bt[N][KP] bf16 ============================
struct WEnt { const float* src; short* dst; int K, N, KP; };
struct WTab { WEnt e[10]; };
__global__ __launch_bounds__(256) void wtrans_all(WTab tab){
  WEnt w = tab.e[blockIdx.y];
  int gid = blockIdx.x*256 + threadIdx.x;
  if (gid >= w.N * w.KP) return;
  int n = gid / w.KP, k = gid - n*w.KP;
  float v = (k < w.K) ? w.src[(size_t)k*w.N + n] : 0.f;
  w.dst[gid] = f2bf(v);
}

// ============================ BatchNorm (batch stats) + ELU -> bf16 ============================
template<int C>
__global__ __launch_bounds__(256) void colstats(const float* __restrict__ H, int M,
                                                float* __restrict__ ssum, float* __restrict__ ssq){
  constexpr int RG = 256 / C;
  int col = threadIdx.x % C;
  int r0  = blockIdx.x * RG + threadIdx.x / C;
  int stride = gridDim.x * RG;
  float s = 0.f, q = 0.f;
  for (int r = r0; r < M; r += stride){
    float v = H[(size_t)r*C + col];
    s += v; q += v*v;
  }
  atomicAdd(&ssum[col], s);
  atomicAdd(&ssq[col],  q);
}

__global__ void bn_finalize(const float* __restrict__ ssum, const float* __restrict__ ssq,
                            const float* __restrict__ g, const float* __restrict__ bt,
                            float* __restrict__ scale, float* __restrict__ shift, int C, float invM){
  int c = blockIdx.x*blockDim.x + threadIdx.x;
  if (c >= C) return;
  float m  = ssum[c]*invM;
  float var = ssq[c]*invM - m*m;
  float sc = g[c] * rsqrtf(var + 1e-5f);
  scale[c] = sc;
  shift[c] = bt[c] - m*sc;
}

template<int C>
__global__ __launch_bounds__(256) void bn_elu_apply_bf(const float* __restrict__ H, short* __restrict__ O,
                                                       int total4,
                                                       const float* __restrict__ sc, const float* __restrict__ sh){
  int i = blockIdx.x*256 + threadIdx.x;
  int stride = gridDim.x*256;
  for (; i < total4; i += stride){
    float4 v = ((const float4*)H)[i];
    int cb = (i*4) & (C-1);
    short4v o;
    o[0] = f2bf(eluf(v.x*sc[cb+0]+sh[cb+0]));
    o[1] = f2bf(eluf(v.y*sc[cb+1]+sh[cb+1]));
    o[2] = f2bf(eluf(v.z*sc[cb+2]+sh[cb+2]));
    o[3] = f2bf(eluf(v.w*sc[cb+3]+sh[cb+3]));
    ((short4v*)O)[i] = o;
  }
}

// ============================ CSR build ============================
__global__ void hist_kernel(const int* __restrict__ d, int E, int* __restrict__ deg){
  int i = blockIdx.x*256 + threadIdx.x;
  if (i < E) atomicAdd(&deg[d[i]], 1);
}

__global__ __launch_bounds__(1024) void scan_kernel(const int* __restrict__ deg, int* __restrict__ offs,
                                                    int* __restrict__ cursor, int n){
  __shared__ int sm[1024];
  __shared__ int carry;
  if (threadIdx.x == 0) carry = 0;
  __syncthreads();
  for (int base = 0; base < n; base += 1024){
    int i = base + threadIdx.x;
    int v = (i < n) ? deg[i] : 0;
    sm[threadIdx.x] = v;
    __syncthreads();
    for (int d = 1; d < 1024; d <<= 1){
      int t = (threadIdx.x >= d) ? sm[threadIdx.x - d] : 0;
      __syncthreads();
      sm[threadIdx.x] += t;
      __syncthreads();
    }
    int excl = sm[threadIdx.x] - v + carry;
    if (i < n){ offs[i] = excl; cursor[i] = excl; }
    __syncthreads();
    if (threadIdx.x == 0) carry += sm[1023];
    __syncthreads();
  }
  if (threadIdx.x == 0) offs[n] = carry;
}

__global__ void scatter_kernel(const int* __restrict__ s, const int* __restrict__ d, int E,
                               int* __restrict__ cursor, int* __restrict__ csr){
  int i = blockIdx.x*256 + threadIdx.x;
  if (i < E){ int pos = atomicAdd(&cursor[d[i]], 1); csr[pos] = s[i]; }
}

// ============================ GAT1 (3 heads x 64), hh1 in bf16 ============================
__global__ __launch_bounds__(256) void gat1_scores_bf(const short* __restrict__ hh,
    const float* __restrict__ as, const float* __restrict__ ad,
    float* __restrict__ ss, float* __restrict__ sd, int n){
  int w = threadIdx.x >> 6, lane = threadIdx.x & 63;
  int row = blockIdx.x*4 + w;
  if (row >= n) return;
  const short* hr = hh + (size_t)row*192;
  float ps[3], pd[3];
  #pragma unroll
  for (int h=0; h<3; h++){
    float v = b2f(hr[h*64 + lane]);
    ps[h] = v * as[h*64+lane];
    pd[h] = v * ad[h*64+lane];
  }
  #pragma unroll
  for (int m=32; m; m>>=1){
    #pragma unroll
    for (int h=0;h<3;h++){ ps[h] += __shfl_xor(ps[h], m); pd[h] += __shfl_xor(pd[h], m); }
  }
  if (lane == 0){
    #pragma unroll
    for (int h=0;h<3;h++){ ss[row*3+h]=ps[h]; sd[row*3+h]=pd[h]; }
  }
}

__global__ __launch_bounds__(256) void gat1_gather_bf(const int* __restrict__ offs, const int* __restrict__ csr,
    const short* __restrict__ hh, const float* __restrict__ ss, const float* __restrict__ sd,
    const float* __restrict__ bias, short* __restrict__ out, int n){
  int w = threadIdx.x >> 6, lane = threadIdx.x & 63;
  int dst = blockIdx.x*4 + w;
  if (dst >= n) return;
  float sd0 = sd[dst*3+0], sd1 = sd[dst*3+1], sd2 = sd[dst*3+2];
  float p0 = __expf(lrelu(ss[dst*3+0]+sd0));
  float p1 = __expf(lrelu(ss[dst*3+1]+sd1));
  float p2 = __expf(lrelu(ss[dst*3+2]+sd2));
  const short* hr = hh + (size_t)dst*192;
  float a0 = p0*b2f(hr[lane]), a1 = p1*b2f(hr[64+lane]), a2 = p2*b2f(hr[128+lane]);
  float d0 = p0, d1 = p1, d2 = p2;
  int pe = offs[dst+1];
  for (int p = offs[dst]; p < pe; ++p){
    int src = csr[p];
    float q0 = __expf(lrelu(ss[src*3+0]+sd0));
    float q1 = __expf(lrelu(ss[src*3+1]+sd1));
    float q2 = __expf(lrelu(ss[src*3+2]+sd2));
    const short* sr = hh + (size_t)src*192;
    a0 += q0*b2f(sr[lane]); a1 += q1*b2f(sr[64+lane]); a2 += q2*b2f(sr[128+lane]);
    d0 += q0; d1 += q1; d2 += q2;
  }
  float v0 = a0/d0 + bias[lane];
  float v1 = a1/d1 + bias[64+lane];
  float v2 = a2/d2 + bias[128+lane];
  short* orow = out + (size_t)dst*192;
  orow[lane]      = f2bf(v0 > 0.f ? v0 : 0.f);
  orow[64+lane]   = f2bf(v1 > 0.f ? v1 : 0.f);
  orow[128+lane]  = f2bf(v2 > 0.f ? v2 : 0.f);
}

// ============================ GAT2/GAT3 (1 head x 30), fused ============================
__global__ __launch_bounds__(256) void gat23_scores(const float* __restrict__ h2, const float* __restrict__ h3v,
    const float* __restrict__ a2s, const float* __restrict__ a2d,
    const float* __restrict__ a3s, const float* __restrict__ a3d,
    float* __restrict__ s2s, float* __restrict__ s2d, float* __restrict__ s3s, float* __restrict__ s3d, int n){
  int w = threadIdx.x >> 6, lane = threadIdx.x & 63;
  int row = blockIdx.x*4 + w;
  if (row >= n) return;
  float p[4] = {0.f,0.f,0.f,0.f};
  if (lane < 30){
    float v2 = h2[(size_t)row*30+lane], v3 = h3v[(size_t)row*30+lane];
    p[0]=v2*a2s[lane]; p[1]=v2*a2d[lane]; p[2]=v3*a3s[lane]; p[3]=v3*a3d[lane];
  }
  #pragma unroll
  for (int m=32; m; m>>=1){
    #pragma unroll
    for (int j=0;j<4;j++) p[j] += __shfl_xor(p[j], m);
  }
  if (lane == 0){ s2s[row]=p[0]; s2d[row]=p[1]; s3s[row]=p[2]; s3d[row]=p[3]; }
}

__global__ __launch_bounds__(256) void gat23_gather(const int* __restrict__ offs, const int* __restrict__ csr,
    const float* __restrict__ hh2, const float* __restrict__ hh3,
    const float* __restrict__ s2s, const float* __restrict__ s2d,
    const float* __restrict__ s3s, const float* __restrict__ s3d,
    const float* __restrict__ b2, const float* __restrict__ b3,
    float* __restrict__ zs, float* __restrict__ mus, float* __restrict__ lvs,
    short* __restrict__ zbf, int n){
  int w = threadIdx.x >> 6, lane = threadIdx.x & 63;
  int dst = blockIdx.x*4 + w;
  if (dst >= n) return;
  bool lo = lane < 32;
  int c = lo ? lane : lane - 32;
  float sdA = s2d[dst], sdB = s3d[dst];
  float p2 = __expf(lrelu(s2s[dst]+sdA));
  float p3 = __expf(lrelu(s3s[dst]+sdB));
  float val = 0.f;
  if (c < 30) val = lo ? hh2[(size_t)dst*30+c] : hh3[(size_t)dst*30+c];
  float acc = (lo ? p2 : p3) * val;
  float den2 = p2, den3 = p3;
  int pe = offs[dst+1];
  for (int p = offs[dst]; p < pe; ++p){
    int src = csr[p];
    float q2 = __expf(lrelu(s2s[src]+sdA));
    float q3 = __expf(lrelu(s3s[src]+sdB));
    float v = 0.f;
    if (c < 30) v = lo ? hh2[(size_t)src*30+c] : hh3[(size_t)src*30+c];
    acc += (lo ? q2 : q3) * v;
    den2 += q2; den3 += q3;
  }
  if (lo){
    if (c < 30){
      float v = acc/den2 + b2[c];
      zs[(size_t)dst*30+c]  = v;
      mus[(size_t)dst*30+c] = v;
      zbf[(size_t)dst*32+c] = f2bf(v);
    } else {
      zbf[(size_t)dst*32+c] = 0;   // pad cols 30,31
    }
  } else if (c < 30){
    lvs[(size_t)dst*30+c] = acc/den3 + b3[c];
  }
}

// ============================ row softmax over 10 ============================
__global__ __launch_bounds__(256) void softmax10(const float* __restrict__ in, float* __restrict__ out, int n){
  int row = blockIdx.x*256 + threadIdx.x;
  if (row >= n) return;
  const float* r = in + (size_t)row*10;
  float m = r[0];
  #pragma unroll
  for (int j=1;j<10;j++) m = fmaxf(m, r[j]);
  float e[10], s = 0.f;
  #pragma unroll
  for (int j=0;j<10;j++){ e[j] = __expf(r[j]-m); s += e[j]; }
  float inv = 1.f/s;
  float* o = out + (size_t)row*10;
  #pragma unroll
  for (int j=0;j<10;j++) o[j] = e[j]*inv;
}

// ============================ host ============================
static inline int cdiv(int a, int b){ return (a + b - 1) / b; }

extern "C" void kernel_launch(void* const* d_in, const int* in_sizes, int n_in,
                              void* d_out, int out_size, void* d_ws, size_t ws_size,
                              hipStream_t stream)
{
  const float* x        = (const float*)d_in[0];
  const int*   ei       = (const int*)  d_in[1];
  const float* enc_w1   = (const float*)d_in[2];
  const float* enc_g1   = (const float*)d_in[4];
  const float* enc_bt1  = (const float*)d_in[5];
  const float* enc_w2   = (const float*)d_in[6];
  const float* enc_g2   = (const float*)d_in[8];
  const float* enc_bt2  = (const float*)d_in[9];
  const float* gat1_w   = (const float*)d_in[10];
  const float* gat1_as  = (const float*)d_in[11];
  const float* gat1_ad  = (const float*)d_in[12];
  const float* gat1_b   = (const float*)d_in[13];
  const float* gat2_w   = (const float*)d_in[14];
  const float* gat2_as  = (const float*)d_in[15];
  const float* gat2_ad  = (const float*)d_in[16];
  const float* gat2_b   = (const float*)d_in[17];
  const float* gat3_w   = (const float*)d_in[18];
  const float* gat3_as  = (const float*)d_in[19];
  const float* gat3_ad  = (const float*)d_in[20];
  const float* gat3_b   = (const float*)d_in[21];
  const float* dec_w1   = (const float*)d_in[22];
  const float* dec_g1   = (const float*)d_in[24];
  const float* dec_bt1  = (const float*)d_in[25];
  const float* dec_w2   = (const float*)d_in[26];
  const float* dec_g2   = (const float*)d_in[28];
  const float* dec_bt2  = (const float*)d_in[29];
  const float* dec_w3   = (const float*)d_in[30];
  const float* dec_b3   = (const float*)d_in[31];
  const float* clu_w1   = (const float*)d_in[32];
  const float* clu_g1   = (const float*)d_in[34];
  const float* clu_bt1  = (const float*)d_in[35];
  const float* clu_w2   = (const float*)d_in[36];
  const float* clu_b2   = (const float*)d_in[37];

  const int N = in_sizes[0] / 1000;
  const int E = in_sizes[1] / 2;
  const int* e_src = ei;
  const int* e_dst = ei + E;

  float* out  = (float*)d_out;
  float* pred = out;
  float* xrec = out + (size_t)N*10;
  float* zs   = xrec + (size_t)N*1000;
  float* mus  = zs  + (size_t)N*30;
  float* lvs  = mus + (size_t)N*30;

  char* ws = (char*)d_ws;
  size_t off = 0;
  auto alloc = [&](size_t bytes)->char*{
    char* p = ws + off;
    off = (off + bytes + 255) & ~(size_t)255;
    return p;
  };
  // weight transposes (bf16)
  short* t_enc1 = (short*)alloc(256*1000*2);
  short* t_enc2 = (short*)alloc(128*256*2);
  short* t_gat1 = (short*)alloc(192*128*2);
  short* t_gat2 = (short*)alloc(30*192*2);
  short* t_gat3 = (short*)alloc(30*192*2);
  short* t_dec1 = (short*)alloc(128*32*2);
  short* t_dec2 = (short*)alloc(256*128*2);
  short* t_dec3 = (short*)alloc(1000*256*2);
  short* t_clu1 = (short*)alloc(128*32*2);
  short* t_clu2 = (short*)alloc(10*128*2);
  // activations
  float* h1f  = (float*)alloc((size_t)N*256*4);
  short* h1b  = (short*)alloc((size_t)N*256*2);
  float* h2f  = (float*)alloc((size_t)N*128*4);
  short* h2b  = (short*)alloc((size_t)N*128*2);
  short* hh1b = (short*)alloc((size_t)N*192*2);
  short* h3b  = (short*)alloc((size_t)N*192*2);
  float* hh2f = (float*)alloc((size_t)N*30*4);
  float* hh3f = (float*)alloc((size_t)N*30*4);
  short* zbf  = (short*)alloc((size_t)N*32*2);
  float* ss1  = (float*)alloc((size_t)N*3*4);
  float* sd1  = (float*)alloc((size_t)N*3*4);
  float* s2s  = (float*)alloc((size_t)N*4);
  float* s2d  = (float*)alloc((size_t)N*4);
  float* s3s  = (float*)alloc((size_t)N*4);
  float* s3d  = (float*)alloc((size_t)N*4);
  float* stats= (float*)alloc(1024*4);
  int*   deg  = (int*)alloc((size_t)(N+1)*4);
  int*   offs = (int*)alloc((size_t)(N+1)*4);
  int*   curp = (int*)alloc((size_t)(N+1)*4);
  int*   csr  = (int*)alloc((size_t)E*4);
  // decoder/cluster aliases (regions dead by the time they're used)
  float* d1f = h2f;                 // 25.6MB
  short* d1b = h2b;                 // 12.8MB
  float* d2f = h1f;                 // 51.2MB
  short* d2b = h1b;                 // 25.6MB
  float* c1f = (float*)hh1b;        // 25.6MB (hh1b+h3b region, both dead)
  short* c1b = (short*)((char*)hh1b + (size_t)N*128*4);  // 12.8MB, still inside hh1b+h3b (38.4MB)
  float* c2  = hh2f;                // 2MB (dead after gat23)
  float* ssum = stats, *ssq = stats+256, *scale = stats+512, *shift = stats+768;

  // --- weight prep ---
  WTab tab;
  tab.e[0] = {enc_w1, t_enc1, 1000, 256, 1000};
  tab.e[1] = {enc_w2, t_enc2, 256, 128, 256};
  tab.e[2] = {gat1_w, t_gat1, 128, 192, 128};
  tab.e[3] = {gat2_w, t_gat2, 192, 30, 192};
  tab.e[4] = {gat3_w, t_gat3, 192, 30, 192};
  tab.e[5] = {dec_w1, t_dec1, 30, 128, 32};
  tab.e[6] = {dec_w2, t_dec2, 128, 256, 128};
  tab.e[7] = {dec_w3, t_dec3, 256, 1000, 256};
  tab.e[8] = {clu_w1, t_clu1, 30, 128, 32};
  tab.e[9] = {clu_w2, t_clu2, 128, 10, 128};
  wtrans_all<<<dim3(cdiv(256000,256), 10), 256, 0, stream>>>(tab);

  // --- CSR build ---
  hipMemsetAsync(deg, 0, (size_t)(N+1)*4, stream);
  hist_kernel<<<cdiv(E,256), 256, 0, stream>>>(e_dst, E, deg);
  scan_kernel<<<1, 1024, 0, stream>>>(deg, offs, curp, N);
  scatter_kernel<<<cdiv(E,256), 256, 0, stream>>>(e_src, e_dst, E, curp, csr);

  auto bn256 = [&](float* Hf, short* Ob, const float* g, const float* bt){
    hipMemsetAsync(stats, 0, 512*4, stream);
    colstats<256><<<256, 256, 0, stream>>>(Hf, N, ssum, ssq);
    bn_finalize<<<1, 256, 0, stream>>>(ssum, ssq, g, bt, scale, shift, 256, 1.f/(float)N);
    bn_elu_apply_bf<256><<<2048, 256, 0, stream>>>(Hf, Ob, N*256/4, scale, shift);
  };
  auto bn128 = [&](float* Hf, short* Ob, const float* g, const float* bt){
    hipMemsetAsync(stats, 0, 512*4, stream);
    colstats<128><<<256, 256, 0, stream>>>(Hf, N, ssum, ssq);
    bn_finalize<<<1, 128, 0, stream>>>(ssum, ssq, g, bt, scale, shift, 128, 1.f/(float)N);
    bn_elu_apply_bf<128><<<2048, 256, 0, stream>>>(Hf, Ob, N*128/4, scale, shift);
  };

  const int MB = cdiv(N, 128);   // 391

  // --- encoder ---
  gemm2<128,32,true,false><<<dim3(MB,2), 256, 0, stream>>>(x, t_enc1, h1f, nullptr, N, 256, 1000, 256);
  bn256(h1f, h1b, enc_g1, enc_bt1);
  gemm2<64,64,false,false><<<dim3(MB,2), 256, 0, stream>>>(h1b, t_enc2, h2f, nullptr, N, 128, 256, 128);
  bn128(h2f, h2b, enc_g2, enc_bt2);

  // --- GAT1 ---
  gemm2<64,64,false,true><<<dim3(MB,3), 256, 0, stream>>>(h2b, t_gat1, hh1b, nullptr, N, 192, 128, 192);
  gat1_scores_bf<<<cdiv(N,4), 256, 0, stream>>>(hh1b, gat1_as, gat1_ad, ss1, sd1, N);
  gat1_gather_bf<<<cdiv(N,4), 256, 0, stream>>>(offs, csr, hh1b, ss1, sd1, gat1_b, h3b, N);

  // --- GAT2 (mu) / GAT3 (logvar) ---
  gemm2<64,64,false,false><<<dim3(MB,1), 256, 0, stream>>>(h3b, t_gat2, hh2f, nullptr, N, 30, 192, 30);
  gemm2<64,64,false,false><<<dim3(MB,1), 256, 0, stream>>>(h3b, t_gat3, hh3f, nullptr, N, 30, 192, 30);
  gat23_scores<<<cdiv(N,4), 256, 0, stream>>>(hh2f, hh3f, gat2_as, gat2_ad, gat3_as, gat3_ad, s2s, s2d, s3s, s3d, N);
  gat23_gather<<<cdiv(N,4), 256, 0, stream>>>(offs, csr, hh2f, hh3f, s2s, s2d, s3s, s3d, gat2_b, gat3_b, zs, mus, lvs, zbf, N);

  // --- decoder ---
  gemm2<64,64,false,false><<<dim3(MB,2), 256, 0, stream>>>(zbf, t_dec1, d1f, nullptr, N, 128, 32, 128);
  bn128(d1f, d1b, dec_g1, dec_bt1);
  gemm2<64,64,false,false><<<dim3(MB,4), 256, 0, stream>>>(d1b, t_dec2, d2f, nullptr, N, 256, 128, 256);
  bn256(d2f, d2b, dec_g2, dec_bt2);
  gemm2<128,32,false,false><<<dim3(MB,8), 256, 0, stream>>>(d2b, t_dec3, xrec, dec_b3, N, 1000, 256, 1000);

  // --- cluster head ---
  gemm2<64,64,false,false><<<dim3(MB,2), 256, 0, stream>>>(zbf, t_clu1, c1f, nullptr, N, 128, 32, 128);
  bn128(c1f, c1b, clu_g1, clu_bt1);
  gemm2<64,64,false,false><<<dim3(MB,1), 256, 0, stream>>>(c1b, t_clu2, c2, clu_b2, N, 10, 128, 10);
  softmax10<<<cdiv(N,256), 256, 0, stream>>>(c2, pred, N);
}

// Round 3
// 745.743 us; speedup vs baseline: 3.3067x; 1.3838x over previous
//
#include <hip/hip_runtime.h>
#include <hip/hip_bf16.h>

typedef short short8 __attribute__((ext_vector_type(8)));
typedef short short4v __attribute__((ext_vector_type(4)));
typedef float f32x4 __attribute__((ext_vector_type(4)));

static __device__ __forceinline__ short f2bf(float f){
  __hip_bfloat16 h = __float2bfloat16(f);
  return __builtin_bit_cast(short, h);
}
static __device__ __forceinline__ float b2f(short s){
  unsigned int u = ((unsigned int)(unsigned short)s) << 16;
  return __builtin_bit_cast(float, u);
}
static __device__ __forceinline__ float lrelu(float x){ return x > 0.f ? x : 0.2f*x; }
static __device__ __forceinline__ float eluf(float x){ return x > 0.f ? x : (__expf(x)-1.f); }
static __device__ __forceinline__ int imin(int a,int b){ return a<b?a:b; }

typedef const __attribute__((address_space(1))) void as1_void;
typedef __attribute__((address_space(3))) void as3_void;
static __device__ __forceinline__ void gload16(const void* g, void* l){
  __builtin_amdgcn_global_load_lds((as1_void*)g, (as3_void*)l, 16, 0, 0);
}
template<int NN> __device__ __forceinline__ void wait_vm(){
  if constexpr (NN==0) asm volatile("s_waitcnt vmcnt(0)" ::: "memory");
  else if constexpr (NN==3) asm volatile("s_waitcnt vmcnt(3)" ::: "memory");
  else if constexpr (NN==4) asm volatile("s_waitcnt vmcnt(4)" ::: "memory");
  else if constexpr (NN==6) asm volatile("s_waitcnt vmcnt(6)" ::: "memory");
  else if constexpr (NN==8) asm volatile("s_waitcnt vmcnt(8)" ::: "memory");
}

// ==================== GEMM (bf16 A): gload_lds ring-4, counted vmcnt ====================
// A: bf16 [M][K] (K mult of 32). Bt: bf16 [NR][KP] rows padded >= grid*BN, KP=K.
template<int BN, bool OBF16, bool CSTATS>
__global__ __launch_bounds__(256) void gemm_g(
    const short* __restrict__ A, const short* __restrict__ Bt,
    void* __restrict__ Cv, const float* __restrict__ bias,
    float* __restrict__ ssum, float* __restrict__ ssq,
    int M, int N, int K, int ldc)
{
  constexpr int BM = 128, BK = 32, GPR = 4;
  constexpr int WN = BN/2, FM = 4, FN = WN/16;
  constexpr int AI = (BM*GPR)/(4*64);            // 2 per-wave A stage instrs
  constexpr int BI_T = (BN*GPR)/64;              // total B stage instrs
  constexpr bool BDUP = (BI_T < 4);
  constexpr int BI = BDUP ? BI_T : BI_T/4;
  constexpr int LPT = AI + BI;                   // per-wave loads per tile
  constexpr int TS = (BM+BN)*BK;                 // shorts per tile
  __shared__ short lds[4][TS];

  const int tid = threadIdx.x, wid = tid>>6, lane = tid&63;
  const int wm = wid>>1, wn = wid&1;
  const int bm = blockIdx.x*BM, bn = blockIdx.y*BN;
  const int lr = lane&15, lg = lane>>4;
  const int nt = K/BK;

  f32x4 acc[FM][FN] = {};

  auto STAGE = [&](int t){
    int buf = t & 3, k0 = t*BK;
    #pragma unroll
    for (int i=0;i<AI;i++){
      int ci = wid*AI + i;
      int c = ci*64 + lane;
      int row = c>>2, g = c&3;
      int gr = imin(bm+row, M-1);
      const short* src = A + (size_t)gr*K + k0 + ((g ^ (row&3))<<3);
      gload16(src, &lds[buf][ci*512]);
    }
    #pragma unroll
    for (int i=0;i<BI;i++){
      int bi = BDUP ? i : wid*BI + i;
      int c = bi*64 + lane;
      int row = c>>2, g = c&3;
      const short* src = Bt + (size_t)(bn+row)*K + k0 + ((g ^ (row&3))<<3);
      gload16(src, &lds[buf][BM*BK + bi*512]);
    }
  };

  for (int s=0; s<3 && s<nt; ++s) STAGE(s);

  for (int t=0; t<nt; ++t){
    int newer = imin(nt, t+3) - t - 1;
    if (newer >= 2) wait_vm<2*LPT>();
    else if (newer == 1) wait_vm<LPT>();
    else wait_vm<0>();
    __builtin_amdgcn_s_barrier();
    __builtin_amdgcn_sched_barrier(0);
    if (t+3 < nt) STAGE(t+3);
    int buf = t & 3;
    short8 af[FM], bf[FN];
    #pragma unroll
    for (int m=0;m<FM;m++){
      int r = wm*64 + m*16 + lr;
      af[m] = *(short8*)&lds[buf][r*BK + ((lg ^ (r&3))<<3)];
    }
    #pragma unroll
    for (int n=0;n<FN;n++){
      int r = wn*WN + n*16 + lr;
      bf[n] = *(short8*)&lds[buf][BM*BK + r*BK + ((lg ^ (r&3))<<3)];
    }
    #pragma unroll
    for (int m=0;m<FM;m++)
      #pragma unroll
      for (int n=0;n<FN;n++)
        acc[m][n] = __builtin_amdgcn_mfma_f32_16x16x32_bf16(af[m], bf[n], acc[m][n], 0, 0, 0);
  }

  #pragma unroll
  for (int m=0;m<FM;m++)
    #pragma unroll
    for (int n=0;n<FN;n++)
      #pragma unroll
      for (int q=0;q<4;q++){
        int row = bm + wm*64 + m*16 + lg*4 + q;
        int col = bn + wn*WN + n*16 + lr;
        if (row < M && col < N){
          float v = acc[m][n][q];
          if (bias) v += bias[col];
          if (OBF16) ((short*)Cv)[(size_t)row*ldc + col] = f2bf(v);
          else       ((float*)Cv)[(size_t)row*ldc + col] = v;
        }
      }
  if (CSTATS){
    #pragma unroll
    for (int n=0;n<FN;n++){
      float s = 0.f, q2 = 0.f;
      #pragma unroll
      for (int m=0;m<FM;m++)
        #pragma unroll
        for (int q=0;q<4;q++){
          int row = bm + wm*64 + m*16 + lg*4 + q;
          if (row < M){ float v = acc[m][n][q]; s += v; q2 += v*v; }
        }
      s  += __shfl_xor(s, 16);  s += __shfl_xor(s, 32);
      q2 += __shfl_xor(q2, 16); q2 += __shfl_xor(q2, 32);
      if (lg == 0){
        int col = bn + wn*WN + n*16 + lr;
        atomicAdd(&ssum[col], s);
        atomicAdd(&ssq[col],  q2);
      }
    }
  }
}

// ==================== GEMM (f32 A): reg-staged depth-2, counted vmcnt (enc1) ====================
__global__ __launch_bounds__(256) void gemm_f(
    const float* __restrict__ A, const short* __restrict__ Bt,
    float* __restrict__ C, float* __restrict__ ssum, float* __restrict__ ssq,
    int M, int N, int K, int KP, int ldc)
{
  constexpr int BM = 128, BN = 128, BK = 32, GPR = 4;
  constexpr int WN = 64, FM = 4, FN = 4;
  __shared__ short lds[2][(BM+BN)*BK];

  const int tid = threadIdx.x, wid = tid>>6, lane = tid&63;
  const int wm = wid>>1, wn = wid&1;
  const int bm = blockIdx.x*BM, bn = blockIdx.y*BN;
  const int lr = lane&15, lg = lane>>4;
  const int nt = (K + BK - 1)/BK;

  f32x4 acc[FM][FN] = {};
  float  raX[2][8], raY[2][8];
  short8 rbX[2], rbY[2];

  auto LOADR = [&](int t, float (&ra)[2][8], short8 (&rb)[2]){
    int k0 = t*BK;
    #pragma unroll
    for (int p=0;p<2;p++){
      int c = p*256 + tid, row = c>>2, g = c&3;
      int gr = imin(bm+row, M-1), k = k0 + g*8;
      if (k + 8 <= K){
        const float* ap = A + (size_t)gr*K + k;
        float4 f0 = *(const float4*)ap, f1 = *(const float4*)(ap+4);
        ra[p][0]=f0.x; ra[p][1]=f0.y; ra[p][2]=f0.z; ra[p][3]=f0.w;
        ra[p][4]=f1.x; ra[p][5]=f1.y; ra[p][6]=f1.z; ra[p][7]=f1.w;
      } else {
        #pragma unroll
        for (int j=0;j<8;j++) ra[p][j] = 0.f;
      }
    }
    #pragma unroll
    for (int p=0;p<2;p++){
      int c = p*256 + tid, row = c>>2, g = c&3;
      rb[p] = *(const short8*)(Bt + (size_t)(bn+row)*KP + k0 + g*8);
    }
  };
  auto WRITE = [&](float (&ra)[2][8], short8 (&rb)[2], int buf){
    #pragma unroll
    for (int p=0;p<2;p++){
      int c = p*256 + tid, row = c>>2, g = c&3;
      short8 o;
      #pragma unroll
      for (int j=0;j<8;j++) o[j] = f2bf(ra[p][j]);
      *(short8*)&lds[buf][row*BK + ((g ^ (row&3))<<3)] = o;
    }
    #pragma unroll
    for (int p=0;p<2;p++){
      int c = p*256 + tid, row = c>>2, g = c&3;
      *(short8*)&lds[buf][(BM+row)*BK + ((g ^ (row&3))<<3)] = rb[p];
    }
  };
  auto MF = [&](int buf){
    short8 af[FM], bf[FN];
    #pragma unroll
    for (int m=0;m<FM;m++){
      int r = wm*64 + m*16 + lr;
      af[m] = *(short8*)&lds[buf][r*BK + ((lg ^ (r&3))<<3)];
    }
    #pragma unroll
    for (int n=0;n<FN;n++){
      int r = wn*WN + n*16 + lr;
      bf[n] = *(short8*)&lds[buf][(BM+r)*BK + ((lg ^ (r&3))<<3)];
    }
    #pragma unroll
    for (int m=0;m<FM;m++)
      #pragma unroll
      for (int n=0;n<FN;n++)
        acc[m][n] = __builtin_amdgcn_mfma_f32_16x16x32_bf16(af[m], bf[n], acc[m][n], 0, 0, 0);
  };

  // prologue
  LOADR(0, raX, rbX);
  if (nt > 1){ LOADR(1, raY, rbY); wait_vm<6>(); } else wait_vm<0>();
  WRITE(raX, rbX, 0);
  asm volatile("s_waitcnt lgkmcnt(0)" ::: "memory");
  __builtin_amdgcn_s_barrier();
  __builtin_amdgcn_sched_barrier(0);

#define GSTEP(T, RAc, RBc, RAw, RBw, BUFC, BUFW) do{                         \
    if ((T)+2 < nt) LOADR((T)+2, RAc, RBc);                                  \
    MF(BUFC);                                                                \
    if ((T)+1 < nt){                                                         \
      if ((T)+2 < nt) wait_vm<6>(); else wait_vm<0>();                       \
      WRITE(RAw, RBw, BUFW);                                                 \
      asm volatile("s_waitcnt lgkmcnt(0)" ::: "memory");                     \
    }                                                                        \
    __builtin_amdgcn_s_barrier();                                            \
    __builtin_amdgcn_sched_barrier(0);                                       \
  }while(0)

  for (int t=0; t<nt; t+=2){
    GSTEP(t,   raX, rbX, raY, rbY, 0, 1);
    if (t+1 < nt) GSTEP(t+1, raY, rbY, raX, rbX, 1, 0);
  }
#undef GSTEP

  #pragma unroll
  for (int m=0;m<FM;m++)
    #pragma unroll
    for (int n=0;n<FN;n++)
      #pragma unroll
      for (int q=0;q<4;q++){
        int row = bm + wm*64 + m*16 + lg*4 + q;
        int col = bn + wn*WN + n*16 + lr;
        if (row < M && col < N) C[(size_t)row*ldc + col] = acc[m][n][q];
      }
  #pragma unroll
  for (int n=0;n<FN;n++){
    float s = 0.f, q2 = 0.f;
    #pragma unroll
    for (int m=0;m<FM;m++)
      #pragma unroll
      for (int q=0;q<4;q++){
        int row = bm + wm*64 + m*16 + lg*4 + q;
        if (row < M){ float v = acc[m][n][q]; s += v; q2 += v*v; }
      }
    s  += __shfl_xor(s, 16);  s += __shfl_xor(s, 32);
    q2 += __shfl_xor(q2, 16); q2 += __shfl_xor(q2, 32);
    if (lg == 0){
      int col = bn + wn*WN + n*16 + lr;
      atomicAdd(&ssum[col], s);
      atomicAdd(&ssq[col],  q2);
    }
  }
}

// ==================== weight transpose/convert ====================
struct WEnt { const float* src; short* dst; int K, N, KP, NR; };
struct WTab { WEnt e[10]; };
__global__ __launch_bounds__(256) void wtrans_all(WTab tab){
  WEnt w = tab.e[blockIdx.y];
  int gid = blockIdx.x*256 + threadIdx.x;
  if (gid >= w.NR * w.KP) return;
  int n = gid / w.KP, k = gid - n*w.KP;
  float v = (k < w.K && n < w.N) ? w.src[(size_t)k*w.N + n] : 0.f;
  w.dst[gid] = f2bf(v);
}

// ==================== BN finalize + apply ====================
__global__ void bn_finalize(const float* __restrict__ ssum, const float* __restrict__ ssq,
                            const float* __restrict__ g, const float* __restrict__ bt,
                            float* __restrict__ scale, float* __restrict__ shift, int C, float invM){
  int c = blockIdx.x*blockDim.x + threadIdx.x;
  if (c >= C) return;
  float m  = ssum[c]*invM;
  float var = ssq[c]*invM - m*m;
  float sc = g[c] * rsqrtf(var + 1e-5f);
  scale[c] = sc;
  shift[c] = bt[c] - m*sc;
}

template<int C>
__global__ __launch_bounds__(256) void bn_elu_apply_bf(const float* __restrict__ H, short* __restrict__ O,
                                                       int total4,
                                                       const float* __restrict__ sc, const float* __restrict__ sh){
  int i = blockIdx.x*256 + threadIdx.x;
  int stride = gridDim.x*256;
  for (; i < total4; i += stride){
    float4 v = ((const float4*)H)[i];
    int cb = (i*4) & (C-1);
    short4v o;
    o[0] = f2bf(eluf(v.x*sc[cb+0]+sh[cb+0]));
    o[1] = f2bf(eluf(v.y*sc[cb+1]+sh[cb+1]));
    o[2] = f2bf(eluf(v.z*sc[cb+2]+sh[cb+2]));
    o[3] = f2bf(eluf(v.w*sc[cb+3]+sh[cb+3]));
    ((short4v*)O)[i] = o;
  }
}

// ==================== CSR build ====================
__global__ void hist_kernel(const int* __restrict__ d, int E, int* __restrict__ deg){
  int i = blockIdx.x*256 + threadIdx.x;
  if (i < E) atomicAdd(&deg[d[i]], 1);
}
__global__ __launch_bounds__(256) void scan1(const int* __restrict__ deg, int* __restrict__ offs,
                                             int* __restrict__ bsum, int n){
  __shared__ int sm[256];
  int tid = threadIdx.x;
  int base = blockIdx.x*1024 + tid*4;
  int v0 = base+0<n ? deg[base+0] : 0;
  int v1 = base+1<n ? deg[base+1] : 0;
  int v2 = base+2<n ? deg[base+2] : 0;
  int v3 = base+3<n ? deg[base+3] : 0;
  int ts = v0+v1+v2+v3;
  sm[tid] = ts;
  __syncthreads();
  #pragma unroll
  for (int d=1; d<256; d<<=1){
    int t = (tid>=d) ? sm[tid-d] : 0;
    __syncthreads();
    sm[tid] += t;
    __syncthreads();
  }
  int ex = sm[tid] - ts;
  if (base+0<n) offs[base+0] = ex;
  if (base+1<n) offs[base+1] = ex+v0;
  if (base+2<n) offs[base+2] = ex+v0+v1;
  if (base+3<n) offs[base+3] = ex+v0+v1+v2;
  if (tid==255) bsum[blockIdx.x] = sm[255];
}
__global__ void scan2(int* __restrict__ bsum, int nb){
  int lane = threadIdx.x;
  int v = lane<nb ? bsum[lane] : 0;
  int incl = v;
  #pragma unroll
  for (int d=1; d<64; d<<=1){
    int t = __shfl_up(incl, d);
    if (lane >= d) incl += t;
  }
  if (lane < nb) bsum[lane] = incl - v;
}
__global__ void scan3(int* __restrict__ offs, const int* __restrict__ bsum,
                      int* __restrict__ cursor, int n, int total){
  int i = blockIdx.x*256 + threadIdx.x;
  if (i < n){ int v = offs[i] + bsum[i>>10]; offs[i]=v; cursor[i]=v; }
  if (i == 0) offs[n] = total;
}
__global__ void scatter_kernel(const int* __restrict__ s, const int* __restrict__ d, int E,
                               int* __restrict__ cursor, int* __restrict__ csr){
  int i = blockIdx.x*256 + threadIdx.x;
  if (i < E){ int pos = atomicAdd(&cursor[d[i]], 1); csr[pos] = s[i]; }
}

// ==================== GAT1 ====================
__global__ __launch_bounds__(256) void gat1_scores_bf(const short* __restrict__ hh,
    const float* __restrict__ as, const float* __restrict__ ad,
    float* __restrict__ ss, float* __restrict__ sd, int n){
  int w = threadIdx.x >> 6, lane = threadIdx.x & 63;
  int row = blockIdx.x*4 + w;
  if (row >= n) return;
  const short* hr = hh + (size_t)row*192;
  float ps[3], pd[3];
  #pragma unroll
  for (int h=0; h<3; h++){
    float v = b2f(hr[h*64 + lane]);
    ps[h] = v * as[h*64+lane];
    pd[h] = v * ad[h*64+lane];
  }
  #pragma unroll
  for (int m=32; m; m>>=1){
    #pragma unroll
    for (int h=0;h<3;h++){ ps[h] += __shfl_xor(ps[h], m); pd[h] += __shfl_xor(pd[h], m); }
  }
  if (lane == 0){
    #pragma unroll
    for (int h=0;h<3;h++){ ss[row*3+h]=ps[h]; sd[row*3+h]=pd[h]; }
  }
}

__global__ __launch_bounds__(256) void gat1_gather_bf(const int* __restrict__ offs, const int* __restrict__ csr,
    const short* __restrict__ hh, const float* __restrict__ ss, const float* __restrict__ sd,
    const float* __restrict__ bias, short* __restrict__ out, int n){
  int w = threadIdx.x >> 6, lane = threadIdx.x & 63;
  int dst = blockIdx.x*4 + w;
  if (dst >= n) return;
  float sd0 = sd[dst*3+0], sd1 = sd[dst*3+1], sd2 = sd[dst*3+2];
  float p0 = __expf(lrelu(ss[dst*3+0]+sd0));
  float p1 = __expf(lrelu(ss[dst*3+1]+sd1));
  float p2 = __expf(lrelu(ss[dst*3+2]+sd2));
  const short* hr = hh + (size_t)dst*192;
  float a0 = p0*b2f(hr[lane]), a1 = p1*b2f(hr[64+lane]), a2 = p2*b2f(hr[128+lane]);
  float d0 = p0, d1 = p1, d2 = p2;
  int p = offs[dst], pe = offs[dst+1];
  for (; p+4 <= pe; p += 4){
    int s0=csr[p], s1=csr[p+1], s2=csr[p+2], s3=csr[p+3];
    float e00=ss[s0*3+0], e01=ss[s0*3+1], e02=ss[s0*3+2];
    float e10=ss[s1*3+0], e11=ss[s1*3+1], e12=ss[s1*3+2];
    float e20=ss[s2*3+0], e21=ss[s2*3+1], e22=ss[s2*3+2];
    float e30=ss[s3*3+0], e31=ss[s3*3+1], e32=ss[s3*3+2];
    const short* r0 = hh + (size_t)s0*192;
    const short* r1 = hh + (size_t)s1*192;
    const short* r2 = hh + (size_t)s2*192;
    const short* r3 = hh + (size_t)s3*192;
    float v00=b2f(r0[lane]), v01=b2f(r0[64+lane]), v02=b2f(r0[128+lane]);
    float v10=b2f(r1[lane]), v11=b2f(r1[64+lane]), v12=b2f(r1[128+lane]);
    float v20=b2f(r2[lane]), v21=b2f(r2[64+lane]), v22=b2f(r2[128+lane]);
    float v30=b2f(r3[lane]), v31=b2f(r3[64+lane]), v32=b2f(r3[128+lane]);
    float q00=__expf(lrelu(e00+sd0)), q01=__expf(lrelu(e01+sd1)), q02=__expf(lrelu(e02+sd2));
    float q10=__expf(lrelu(e10+sd0)), q11=__expf(lrelu(e11+sd1)), q12=__expf(lrelu(e12+sd2));
    float q20=__expf(lrelu(e20+sd0)), q21=__expf(lrelu(e21+sd1)), q22=__expf(lrelu(e22+sd2));
    float q30=__expf(lrelu(e30+sd0)), q31=__expf(lrelu(e31+sd1)), q32=__expf(lrelu(e32+sd2));
    a0 += q00*v00 + q10*v10 + q20*v20 + q30*v30;
    a1 += q01*v01 + q11*v11 + q21*v21 + q31*v31;
    a2 += q02*v02 + q12*v12 + q22*v22 + q32*v32;
    d0 += q00+q10+q20+q30;
    d1 += q01+q11+q21+q31;
    d2 += q02+q12+q22+q32;
  }
  for (; p < pe; ++p){
    int src = csr[p];
    float q0 = __expf(lrelu(ss[src*3+0]+sd0));
    float q1 = __expf(lrelu(ss[src*3+1]+sd1));
    float q2 = __expf(lrelu(ss[src*3+2]+sd2));
    const short* sr = hh + (size_t)src*192;
    a0 += q0*b2f(sr[lane]); a1 += q1*b2f(sr[64+lane]); a2 += q2*b2f(sr[128+lane]);
    d0 += q0; d1 += q1; d2 += q2;
  }
  float v0 = a0/d0 + bias[lane];
  float v1 = a1/d1 + bias[64+lane];
  float v2 = a2/d2 + bias[128+lane];
  short* orow = out + (size_t)dst*192;
  orow[lane]      = f2bf(v0 > 0.f ? v0 : 0.f);
  orow[64+lane]   = f2bf(v1 > 0.f ? v1 : 0.f);
  orow[128+lane]  = f2bf(v2 > 0.f ? v2 : 0.f);
}

// ==================== GAT2/3 fused ====================
__global__ __launch_bounds__(256) void gat23_scores(const float* __restrict__ h2, const float* __restrict__ h3v,
    const float* __restrict__ a2s, const float* __restrict__ a2d,
    const float* __restrict__ a3s, const float* __restrict__ a3d,
    float* __restrict__ s2s, float* __restrict__ s2d, float* __restrict__ s3s, float* __restrict__ s3d, int n){
  int w = threadIdx.x >> 6, lane = threadIdx.x & 63;
  int row = blockIdx.x*4 + w;
  if (row >= n) return;
  float p[4] = {0.f,0.f,0.f,0.f};
  if (lane < 30){
    float v2 = h2[(size_t)row*30+lane], v3 = h3v[(size_t)row*30+lane];
    p[0]=v2*a2s[lane]; p[1]=v2*a2d[lane]; p[2]=v3*a3s[lane]; p[3]=v3*a3d[lane];
  }
  #pragma unroll
  for (int m=32; m; m>>=1){
    #pragma unroll
    for (int j=0;j<4;j++) p[j] += __shfl_xor(p[j], m);
  }
  if (lane == 0){ s2s[row]=p[0]; s2d[row]=p[1]; s3s[row]=p[2]; s3d[row]=p[3]; }
}

__global__ __launch_bounds__(256) void gat23_gather(const int* __restrict__ offs, const int* __restrict__ csr,
    const float* __restrict__ hh2, const float* __restrict__ hh3,
    const float* __restrict__ s2s, const float* __restrict__ s2d,
    const float* __restrict__ s3s, const float* __restrict__ s3d,
    const float* __restrict__ b2, const float* __restrict__ b3,
    float* __restrict__ zs, float* __restrict__ mus, float* __restrict__ lvs,
    short* __restrict__ zbf, int n){
  int w = threadIdx.x >> 6, lane = threadIdx.x & 63;
  int dst = blockIdx.x*4 + w;
  if (dst >= n) return;
  bool lo = lane < 32;
  int c = lo ? lane : lane - 32;
  const float* hhx = lo ? hh2 : hh3;
  float sdA = s2d[dst], sdB = s3d[dst];
  float sdx = lo ? sdA : sdB;
  const float* ssx = lo ? s2s : s3s;
  float p2 = __expf(lrelu(s2s[dst]+sdA));
  float p3 = __expf(lrelu(s3s[dst]+sdB));
  float val = (c < 30) ? hhx[(size_t)dst*30+c] : 0.f;
  float acc = (lo ? p2 : p3) * val;
  float den2 = p2, den3 = p3;
  int p = offs[dst], pe = offs[dst+1];
  for (; p+4 <= pe; p += 4){
    int s0=csr[p], s1=csr[p+1], s2i=csr[p+2], s3i=csr[p+3];
    float eA0=ssx[s0], eA1=ssx[s1], eA2=ssx[s2i], eA3=ssx[s3i];
    float f20=s2s[s0], f21=s2s[s1], f22=s2s[s2i], f23=s2s[s3i];
    float f30=s3s[s0], f31=s3s[s1], f32=s3s[s2i], f33=s3s[s3i];
    float v0 = (c<30)? hhx[(size_t)s0*30+c] : 0.f;
    float v1 = (c<30)? hhx[(size_t)s1*30+c] : 0.f;
    float v2 = (c<30)? hhx[(size_t)s2i*30+c] : 0.f;
    float v3 = (c<30)? hhx[(size_t)s3i*30+c] : 0.f;
    float qx0=__expf(lrelu(eA0+sdx)), qx1=__expf(lrelu(eA1+sdx));
    float qx2=__expf(lrelu(eA2+sdx)), qx3=__expf(lrelu(eA3+sdx));
    acc += qx0*v0 + qx1*v1 + qx2*v2 + qx3*v3;
    den2 += __expf(lrelu(f20+sdA)) + __expf(lrelu(f21+sdA)) + __expf(lrelu(f22+sdA)) + __expf(lrelu(f23+sdA));
    den3 += __expf(lrelu(f30+sdB)) + __expf(lrelu(f31+sdB)) + __expf(lrelu(f32+sdB)) + __expf(lrelu(f33+sdB));
  }
  for (; p < pe; ++p){
    int src = csr[p];
    float q2 = __expf(lrelu(s2s[src]+sdA));
    float q3 = __expf(lrelu(s3s[src]+sdB));
    float v = (c<30)? hhx[(size_t)src*30+c] : 0.f;
    acc += (lo ? q2 : q3) * v;
    den2 += q2; den3 += q3;
  }
  if (lo){
    if (c < 30){
      float v = acc/den2 + b2[c];
      zs[(size_t)dst*30+c]  = v;
      mus[(size_t)dst*30+c] = v;
      zbf[(size_t)dst*32+c] = f2bf(v);
    } else {
      zbf[(size_t)dst*32+c] = 0;
    }
  } else if (c < 30){
    lvs[(size_t)dst*30+c] = acc/den3 + b3[c];
  }
}

// ==================== softmax ====================
__global__ __launch_bounds__(256) void softmax10(const float* __restrict__ in, float* __restrict__ out, int n){
  int row = blockIdx.x*256 + threadIdx.x;
  if (row >= n) return;
  const float* r = in + (size_t)row*10;
  float m = r[0];
  #pragma unroll
  for (int j=1;j<10;j++) m = fmaxf(m, r[j]);
  float e[10], s = 0.f;
  #pragma unroll
  for (int j=0;j<10;j++){ e[j] = __expf(r[j]-m); s += e[j]; }
  float inv = 1.f/s;
  float* o = out + (size_t)row*10;
  #pragma unroll
  for (int j=0;j<10;j++) o[j] = e[j]*inv;
}

// ==================== host ====================
static inline int cdiv(int a, int b){ return (a + b - 1) / b; }

extern "C" void kernel_launch(void* const* d_in, const int* in_sizes, int n_in,
                              void* d_out, int out_size, void* d_ws, size_t ws_size,
                              hipStream_t stream)
{
  const float* x        = (const float*)d_in[0];
  const int*   ei       = (const int*)  d_in[1];
  const float* enc_w1   = (const float*)d_in[2];
  const float* enc_g1   = (const float*)d_in[4];
  const float* enc_bt1  = (const float*)d_in[5];
  const float* enc_w2   = (const float*)d_in[6];
  const float* enc_g2   = (const float*)d_in[8];
  const float* enc_bt2  = (const float*)d_in[9];
  const float* gat1_w   = (const float*)d_in[10];
  const float* gat1_as  = (const float*)d_in[11];
  const float* gat1_ad  = (const float*)d_in[12];
  const float* gat1_b   = (const float*)d_in[13];
  const float* gat2_w   = (const float*)d_in[14];
  const float* gat2_as  = (const float*)d_in[15];
  const float* gat2_ad  = (const float*)d_in[16];
  const float* gat2_b   = (const float*)d_in[17];
  const float* gat3_w   = (const float*)d_in[18];
  const float* gat3_as  = (const float*)d_in[19];
  const float* gat3_ad  = (const float*)d_in[20];
  const float* gat3_b   = (const float*)d_in[21];
  const float* dec_w1   = (const float*)d_in[22];
  const float* dec_g1   = (const float*)d_in[24];
  const float* dec_bt1  = (const float*)d_in[25];
  const float* dec_w2   = (const float*)d_in[26];
  const float* dec_g2   = (const float*)d_in[28];
  const float* dec_bt2  = (const float*)d_in[29];
  const float* dec_w3   = (const float*)d_in[30];
  const float* dec_b3   = (const float*)d_in[31];
  const float* clu_w1   = (const float*)d_in[32];
  const float* clu_g1   = (const float*)d_in[34];
  const float* clu_bt1  = (const float*)d_in[35];
  const float* clu_w2   = (const float*)d_in[36];
  const float* clu_b2   = (const float*)d_in[37];

  const int N = in_sizes[0] / 1000;
  const int E = in_sizes[1] / 2;
  const int* e_src = ei;
  const int* e_dst = ei + E;

  float* out  = (float*)d_out;
  float* pred = out;
  float* xrec = out + (size_t)N*10;
  float* zs   = xrec + (size_t)N*1000;
  float* mus  = zs  + (size_t)N*30;
  float* lvs  = mus + (size_t)N*30;

  char* ws = (char*)d_ws;
  size_t off = 0;
  auto alloc = [&](size_t bytes)->char*{
    char* p = ws + off;
    off = (off + bytes + 255) & ~(size_t)255;
    return p;
  };
  short* t_enc1 = (short*)alloc(256*1024*2);
  short* t_enc2 = (short*)alloc(128*256*2);
  short* t_gat1 = (short*)alloc(192*128*2);
  short* t_gat2 = (short*)alloc(32*192*2);
  short* t_gat3 = (short*)alloc(32*192*2);
  short* t_dec1 = (short*)alloc(128*32*2);
  short* t_dec2 = (short*)alloc(256*128*2);
  short* t_dec3 = (short*)alloc(1024*256*2);
  short* t_clu1 = (short*)alloc(128*32*2);
  short* t_clu2 = (short*)alloc(32*128*2);
  float* h1f  = (float*)alloc((size_t)N*256*4);
  short* h1b  = (short*)alloc((size_t)N*256*2);
  float* h2f  = (float*)alloc((size_t)N*128*4);
  short* h2b  = (short*)alloc((size_t)N*128*2);
  short* hh1b = (short*)alloc((size_t)N*192*2);
  short* h3b  = (short*)alloc((size_t)N*192*2);
  float* hh2f = (float*)alloc((size_t)N*30*4);
  float* hh3f = (float*)alloc((size_t)N*30*4);
  short* zbf  = (short*)alloc((size_t)N*32*2);
  float* ss1  = (float*)alloc((size_t)N*3*4);
  float* sd1  = (float*)alloc((size_t)N*3*4);
  float* s2s  = (float*)alloc((size_t)N*4);
  float* s2d  = (float*)alloc((size_t)N*4);
  float* s3s  = (float*)alloc((size_t)N*4);
  float* s3d  = (float*)alloc((size_t)N*4);
  float* stats= (float*)alloc(1024*4);
  int*   deg  = (int*)alloc((size_t)(N+1)*4);
  int*   offs = (int*)alloc((size_t)(N+1)*4);
  int*   curp = (int*)alloc((size_t)(N+1)*4);
  int*   bsum = (int*)alloc(256*4);
  int*   csr  = (int*)alloc((size_t)E*4);
  float* d1f = h2f;
  short* d1b = h2b;
  float* d2f = h1f;
  short* d2b = h1b;
  float* c1f = (float*)hh1b;
  short* c1b = (short*)((char*)hh1b + (size_t)N*128*4);
  float* c2  = hh2f;
  float* ssum = stats, *ssq = stats+256, *scale = stats+512, *shift = stats+768;

  // weight prep
  WTab tab;
  tab.e[0] = {enc_w1, t_enc1, 1000, 256, 1024, 256};
  tab.e[1] = {enc_w2, t_enc2, 256, 128, 256, 128};
  tab.e[2] = {gat1_w, t_gat1, 128, 192, 128, 192};
  tab.e[3] = {gat2_w, t_gat2, 192, 30, 192, 32};
  tab.e[4] = {gat3_w, t_gat3, 192, 30, 192, 32};
  tab.e[5] = {dec_w1, t_dec1, 30, 128, 32, 128};
  tab.e[6] = {dec_w2, t_dec2, 128, 256, 128, 256};
  tab.e[7] = {dec_w3, t_dec3, 256, 1000, 256, 1024};
  tab.e[8] = {clu_w1, t_clu1, 30, 128, 32, 128};
  tab.e[9] = {clu_w2, t_clu2, 128, 10, 128, 32};
  wtrans_all<<<dim3(1024, 10), 256, 0, stream>>>(tab);

  // CSR
  hipMemsetAsync(deg, 0, (size_t)(N+1)*4, stream);
  hist_kernel<<<cdiv(E,256), 256, 0, stream>>>(e_dst, E, deg);
  int nb = cdiv(N, 1024);
  scan1<<<nb, 256, 0, stream>>>(deg, offs, bsum, N);
  scan2<<<1, 64, 0, stream>>>(bsum, nb);
  scan3<<<cdiv(N,256), 256, 0, stream>>>(offs, bsum, curp, N, E);
  scatter_kernel<<<cdiv(E,256), 256, 0, stream>>>(e_src, e_dst, E, curp, csr);

  const int MB = cdiv(N, 128);

  auto bnfin = [&](int C, const float* g, const float* bt){
    bn_finalize<<<1, C, 0, stream>>>(ssum, ssq, g, bt, scale, shift, C, 1.f/(float)N);
  };

  // encoder L1 (f32 A path, fused colstats)
  hipMemsetAsync(stats, 0, 512*4, stream);
  gemm_f<<<dim3(MB,2), 256, 0, stream>>>(x, t_enc1, h1f, ssum, ssq, N, 256, 1000, 1024, 256);
  bnfin(256, enc_g1, enc_bt1);
  bn_elu_apply_bf<256><<<2048, 256, 0, stream>>>(h1f, h1b, N*256/4, scale, shift);

  // encoder L2
  hipMemsetAsync(stats, 0, 512*4, stream);
  gemm_g<128,false,true><<<dim3(MB,1), 256, 0, stream>>>(h1b, t_enc2, h2f, nullptr, ssum, ssq, N, 128, 256, 128);
  bnfin(128, enc_g2, enc_bt2);
  bn_elu_apply_bf<128><<<2048, 256, 0, stream>>>(h2f, h2b, N*128/4, scale, shift);

  // GAT1
  gemm_g<64,true,false><<<dim3(MB,3), 256, 0, stream>>>(h2b, t_gat1, hh1b, nullptr, nullptr, nullptr, N, 192, 128, 192);
  gat1_scores_bf<<<cdiv(N,4), 256, 0, stream>>>(hh1b, gat1_as, gat1_ad, ss1, sd1, N);
  gat1_gather_bf<<<cdiv(N,4), 256, 0, stream>>>(offs, csr, hh1b, ss1, sd1, gat1_b, h3b, N);

  // GAT2/GAT3
  gemm_g<32,false,false><<<dim3(MB,1), 256, 0, stream>>>(h3b, t_gat2, hh2f, nullptr, nullptr, nullptr, N, 30, 192, 30);
  gemm_g<32,false,false><<<dim3(MB,1), 256, 0, stream>>>(h3b, t_gat3, hh3f, nullptr, nullptr, nullptr, N, 30, 192, 30);
  gat23_scores<<<cdiv(N,4), 256, 0, stream>>>(hh2f, hh3f, gat2_as, gat2_ad, gat3_as, gat3_ad, s2s, s2d, s3s, s3d, N);
  gat23_gather<<<cdiv(N,4), 256, 0, stream>>>(offs, csr, hh2f, hh3f, s2s, s2d, s3s, s3d, gat2_b, gat3_b, zs, mus, lvs, zbf, N);

  // decoder
  hipMemsetAsync(stats, 0, 512*4, stream);
  gemm_g<128,false,true><<<dim3(MB,1), 256, 0, stream>>>(zbf, t_dec1, d1f, nullptr, ssum, ssq, N, 128, 32, 128);
  bnfin(128, dec_g1, dec_bt1);
  bn_elu_apply_bf<128><<<2048, 256, 0, stream>>>(d1f, d1b, N*128/4, scale, shift);

  hipMemsetAsync(stats, 0, 512*4, stream);
  gemm_g<128,false,true><<<dim3(MB,2), 256, 0, stream>>>(d1b, t_dec2, d2f, nullptr, ssum, ssq, N, 256, 128, 256);
  bnfin(256, dec_g2, dec_bt2);
  bn_elu_apply_bf<256><<<2048, 256, 0, stream>>>(d2f, d2b, N*256/4, scale, shift);

  gemm_g<128,false,false><<<dim3(MB,8), 256, 0, stream>>>(d2b, t_dec3, xrec, dec_b3, nullptr, nullptr, N, 1000, 256, 1000);

  // cluster head
  hipMemsetAsync(stats, 0, 512*4, stream);
  gemm_g<128,false,true><<<dim3(MB,1), 256, 0, stream>>>(zbf, t_clu1, c1f, nullptr, ssum, ssq, N, 128, 32, 128);
  bnfin(128, clu_g1, clu_bt1);
  bn_elu_apply_bf<128><<<2048, 256, 0, stream>>>(c1f, c1b, N*128/4, scale, shift);

  gemm_g<32,false,false><<<dim3(MB,1), 256, 0, stream>>>(c1b, t_clu2, c2, clu_b2, nullptr, nullptr, N, 10, 128, 10);
  softmax10<<<cdiv(N,256), 256, 0, stream>>>(c2, pred, N);
}

// Round 4
// 701.461 us; speedup vs baseline: 3.5155x; 1.0631x over previous
//
#include <hip/hip_runtime.h>
#include <hip/hip_bf16.h>

typedef short short8 __attribute__((ext_vector_type(8)));
typedef short short4v __attribute__((ext_vector_type(4)));
typedef float f32x4 __attribute__((ext_vector_type(4)));

static __device__ __forceinline__ short f2bf(float f){
  __hip_bfloat16 h = __float2bfloat16(f);
  return __builtin_bit_cast(short, h);
}
static __device__ __forceinline__ float b2f(short s){
  unsigned int u = ((unsigned int)(unsigned short)s) << 16;
  return __builtin_bit_cast(float, u);
}
static __device__ __forceinline__ float lrelu(float x){ return x > 0.f ? x : 0.2f*x; }
static __device__ __forceinline__ float eluf(float x){ return x > 0.f ? x : (__expf(x)-1.f); }
static __device__ __forceinline__ int imin(int a,int b){ return a<b?a:b; }

typedef const __attribute__((address_space(1))) void as1_void;
typedef __attribute__((address_space(3))) void as3_void;
static __device__ __forceinline__ void gload16(const void* g, void* l){
  __builtin_amdgcn_global_load_lds((as1_void*)g, (as3_void*)l, 16, 0, 0);
}
template<int NN> __device__ __forceinline__ void wait_vm(){
  if constexpr (NN==0) asm volatile("s_waitcnt vmcnt(0)" ::: "memory");
  else if constexpr (NN==3) asm volatile("s_waitcnt vmcnt(3)" ::: "memory");
  else if constexpr (NN==4) asm volatile("s_waitcnt vmcnt(4)" ::: "memory");
  else if constexpr (NN==6) asm volatile("s_waitcnt vmcnt(6)" ::: "memory");
  else if constexpr (NN==8) asm volatile("s_waitcnt vmcnt(8)" ::: "memory");
}

// ==================== x f32 -> bf16 convert (streaming) ====================
__global__ __launch_bounds__(256) void cvt_x(const float* __restrict__ x, short* __restrict__ xb, int M){
  int row = blockIdx.x*2 + (threadIdx.x>>7);
  int c8  = (threadIdx.x&127)*8;
  if (row >= M || c8 >= 1000) return;
  const float* p = x + (size_t)row*1000 + c8;
  float4 f0 = *(const float4*)p, f1 = *(const float4*)(p+4);
  short8 o;
  o[0]=f2bf(f0.x);o[1]=f2bf(f0.y);o[2]=f2bf(f0.z);o[3]=f2bf(f0.w);
  o[4]=f2bf(f1.x);o[5]=f2bf(f1.y);o[6]=f2bf(f1.z);o[7]=f2bf(f1.w);
  *(short8*)&xb[(size_t)row*1000 + c8] = o;
}

// ==================== GEMM: gload_lds ring-4, counted vmcnt ====================
// A: bf16 [M][lda]. Bt: bf16 [NR][ldb], rows/cols zero-padded. K arbitrary; B must
// be zero for k in [K, round_up(K,32)) so over-read A garbage contributes 0.
template<int BN, bool OBF16, bool CSTATS>
__global__ __launch_bounds__(256) void gemm_g(
    const short* __restrict__ A, int lda, const short* __restrict__ Bt, int ldb,
    void* __restrict__ Cv, const float* __restrict__ bias,
    float* __restrict__ ssum, float* __restrict__ ssq,
    int M, int N, int K, int ldc)
{
  constexpr int BM = 128, BK = 32, GPR = 4;
  constexpr int WN = BN/2, FM = 4, FN = WN/16;
  constexpr int AI = (BM*GPR)/(4*64);
  constexpr int BI_T = (BN*GPR)/64;
  constexpr bool BDUP = (BI_T < 4);
  constexpr int BI = BDUP ? BI_T : BI_T/4;
  constexpr int LPT = AI + BI;
  constexpr int TS = (BM+BN)*BK;
  __shared__ short lds[4][TS];

  const int tid = threadIdx.x, wid = tid>>6, lane = tid&63;
  const int wm = wid>>1, wn = wid&1;
  const int bm = blockIdx.x*BM, bn = blockIdx.y*BN;
  const int lr = lane&15, lg = lane>>4;
  const int nt = (K + BK - 1)/BK;

  f32x4 acc[FM][FN] = {};

  auto STAGE = [&](int t){
    int buf = t & 3, k0 = t*BK;
    #pragma unroll
    for (int i=0;i<AI;i++){
      int ci = wid*AI + i;
      int c = ci*64 + lane;
      int row = c>>2, g = c&3;
      int gr = imin(bm+row, M-1);
      const short* src = A + (size_t)gr*lda + k0 + ((g ^ (row&3))<<3);
      gload16(src, &lds[buf][ci*512]);
    }
    #pragma unroll
    for (int i=0;i<BI;i++){
      int bi = BDUP ? i : wid*BI + i;
      int c = bi*64 + lane;
      int row = c>>2, g = c&3;
      const short* src = Bt + (size_t)(bn+row)*ldb + k0 + ((g ^ (row&3))<<3);
      gload16(src, &lds[buf][BM*BK + bi*512]);
    }
  };

  for (int s=0; s<3 && s<nt; ++s) STAGE(s);

  for (int t=0; t<nt; ++t){
    int newer = imin(nt, t+3) - t - 1;
    if (newer >= 2) wait_vm<2*LPT>();
    else if (newer == 1) wait_vm<LPT>();
    else wait_vm<0>();
    __builtin_amdgcn_s_barrier();
    __builtin_amdgcn_sched_barrier(0);
    if (t+3 < nt) STAGE(t+3);
    int buf = t & 3;
    short8 af[FM], bf[FN];
    #pragma unroll
    for (int m=0;m<FM;m++){
      int r = wm*64 + m*16 + lr;
      af[m] = *(short8*)&lds[buf][r*BK + ((lg ^ (r&3))<<3)];
    }
    #pragma unroll
    for (int n=0;n<FN;n++){
      int r = wn*WN + n*16 + lr;
      bf[n] = *(short8*)&lds[buf][BM*BK + r*BK + ((lg ^ (r&3))<<3)];
    }
    #pragma unroll
    for (int m=0;m<FM;m++)
      #pragma unroll
      for (int n=0;n<FN;n++)
        acc[m][n] = __builtin_amdgcn_mfma_f32_16x16x32_bf16(af[m], bf[n], acc[m][n], 0, 0, 0);
  }

  #pragma unroll
  for (int m=0;m<FM;m++)
    #pragma unroll
    for (int n=0;n<FN;n++)
      #pragma unroll
      for (int q=0;q<4;q++){
        int row = bm + wm*64 + m*16 + lg*4 + q;
        int col = bn + wn*WN + n*16 + lr;
        if (row < M && col < N){
          float v = acc[m][n][q];
          if (bias) v += bias[col];
          if (OBF16) ((short*)Cv)[(size_t)row*ldc + col] = f2bf(v);
          else       ((float*)Cv)[(size_t)row*ldc + col] = v;
        }
      }
  if (CSTATS){
    #pragma unroll
    for (int n=0;n<FN;n++){
      float s = 0.f, q2 = 0.f;
      #pragma unroll
      for (int m=0;m<FM;m++)
        #pragma unroll
        for (int q=0;q<4;q++){
          int row = bm + wm*64 + m*16 + lg*4 + q;
          if (row < M){ float v = acc[m][n][q]; s += v; q2 += v*v; }
        }
      s  += __shfl_xor(s, 16);  s += __shfl_xor(s, 32);
      q2 += __shfl_xor(q2, 16); q2 += __shfl_xor(q2, 32);
      if (lg == 0){
        int col = bn + wn*WN + n*16 + lr;
        atomicAdd(&ssum[col], s);
        atomicAdd(&ssq[col],  q2);
      }
    }
  }
}

// ==================== weight transpose/convert ====================
struct WEnt { const float* src; short* dst; int K, N, KP, NR; };
struct WTab { WEnt e[10]; };
__global__ __launch_bounds__(256) void wtrans_all(WTab tab){
  WEnt w = tab.e[blockIdx.y];
  int gid = blockIdx.x*256 + threadIdx.x;
  if (gid >= w.NR * w.KP) return;
  int n = gid / w.KP, k = gid - n*w.KP;
  float v = (k < w.K && n < w.N) ? w.src[(size_t)k*w.N + n] : 0.f;
  w.dst[gid] = f2bf(v);
}

// ==================== BN (finalize folded in) + ELU -> bf16 ====================
template<int C>
__global__ __launch_bounds__(256) void bn_elu_apply2(const float* __restrict__ H, short* __restrict__ O,
    int M, float invM,
    const float* __restrict__ ssum, const float* __restrict__ ssq,
    const float* __restrict__ g, const float* __restrict__ bt){
  __shared__ float sc[C], sh[C];
  for (int c = threadIdx.x; c < C; c += 256){
    float mn  = ssum[c]*invM;
    float var = ssq[c]*invM - mn*mn;
    float s = g[c]*rsqrtf(var + 1e-5f);
    sc[c] = s; sh[c] = bt[c] - mn*s;
  }
  __syncthreads();
  int total4 = M*(C/4);
  for (int i = blockIdx.x*256+threadIdx.x; i < total4; i += gridDim.x*256){
    float4 v = ((const float4*)H)[i];
    int cb = (i*4) & (C-1);
    short4v o;
    o[0] = f2bf(eluf(v.x*sc[cb+0]+sh[cb+0]));
    o[1] = f2bf(eluf(v.y*sc[cb+1]+sh[cb+1]));
    o[2] = f2bf(eluf(v.z*sc[cb+2]+sh[cb+2]));
    o[3] = f2bf(eluf(v.w*sc[cb+3]+sh[cb+3]));
    ((short4v*)O)[i] = o;
  }
}

// combined dec1|clu1: H [M][256] -> d1b [M][128], c1b [M][128]
__global__ __launch_bounds__(256) void bn_elu_split(const float* __restrict__ H,
    short* __restrict__ Od, short* __restrict__ Oc, int M, float invM,
    const float* __restrict__ ssum, const float* __restrict__ ssq,
    const float* __restrict__ gd, const float* __restrict__ btd,
    const float* __restrict__ gc, const float* __restrict__ btc){
  __shared__ float sc[256], sh[256];
  {
    int c = threadIdx.x;
    float mn  = ssum[c]*invM;
    float var = ssq[c]*invM - mn*mn;
    float gg = (c<128) ? gd[c] : gc[c-128];
    float bb = (c<128) ? btd[c] : btc[c-128];
    float s = gg*rsqrtf(var + 1e-5f);
    sc[c] = s; sh[c] = bb - mn*s;
  }
  __syncthreads();
  int total4 = M*64;
  for (int i = blockIdx.x*256+threadIdx.x; i < total4; i += gridDim.x*256){
    float4 v = ((const float4*)H)[i];
    int cb = (i*4) & 255;
    short4v o;
    o[0] = f2bf(eluf(v.x*sc[cb+0]+sh[cb+0]));
    o[1] = f2bf(eluf(v.y*sc[cb+1]+sh[cb+1]));
    o[2] = f2bf(eluf(v.z*sc[cb+2]+sh[cb+2]));
    o[3] = f2bf(eluf(v.w*sc[cb+3]+sh[cb+3]));
    int row = i>>6;
    short* O = (cb < 128) ? Od : Oc;
    *(short4v*)&O[(size_t)row*128 + (cb&127)] = o;
  }
}

// ==================== CSR build ====================
__global__ void hist_kernel(const int* __restrict__ d, int E, int* __restrict__ deg){
  int i = blockIdx.x*256 + threadIdx.x;
  if (i < E) atomicAdd(&deg[d[i]], 1);
}
__global__ __launch_bounds__(256) void scan1(const int* __restrict__ deg, int* __restrict__ offs,
                                             int* __restrict__ bsum, int n){
  __shared__ int sm[256];
  int tid = threadIdx.x;
  int base = blockIdx.x*1024 + tid*4;
  int v0 = base+0<n ? deg[base+0] : 0;
  int v1 = base+1<n ? deg[base+1] : 0;
  int v2 = base+2<n ? deg[base+2] : 0;
  int v3 = base+3<n ? deg[base+3] : 0;
  int ts = v0+v1+v2+v3;
  sm[tid] = ts;
  __syncthreads();
  #pragma unroll
  for (int d=1; d<256; d<<=1){
    int t = (tid>=d) ? sm[tid-d] : 0;
    __syncthreads();
    sm[tid] += t;
    __syncthreads();
  }
  int ex = sm[tid] - ts;
  if (base+0<n) offs[base+0] = ex;
  if (base+1<n) offs[base+1] = ex+v0;
  if (base+2<n) offs[base+2] = ex+v0+v1;
  if (base+3<n) offs[base+3] = ex+v0+v1+v2;
  if (tid==255) bsum[blockIdx.x] = sm[255];
}
// scan3 with block-prefix computed inline (one wave sums bsum[0..tgt))
__global__ __launch_bounds__(256) void scan3(int* __restrict__ offs, const int* __restrict__ bsum,
                      int* __restrict__ cursor, int n, int total){
  __shared__ int base_sm;
  int tgt = blockIdx.x >> 2;         // 256 idx/block, 1024 idx per bsum entry
  if (threadIdx.x < 64){
    int j = threadIdx.x;
    int v = (j < tgt) ? bsum[j] : 0;
    #pragma unroll
    for (int d=32; d; d>>=1) v += __shfl_xor(v, d);
    if (j == 0) base_sm = v;
  }
  __syncthreads();
  int i = blockIdx.x*256 + threadIdx.x;
  if (i < n){ int v = offs[i] + base_sm; offs[i]=v; cursor[i]=v; }
  if (i == 0) offs[n] = total;
}
__global__ void scatter_kernel(const int* __restrict__ s, const int* __restrict__ d, int E,
                               int* __restrict__ cursor, int* __restrict__ csr){
  int i = blockIdx.x*256 + threadIdx.x;
  if (i < E){ int pos = atomicAdd(&cursor[d[i]], 1); csr[pos] = s[i]; }
}

// ==================== GAT1 ====================
__global__ __launch_bounds__(256) void gat1_scores_bf(const short* __restrict__ hh,
    const float* __restrict__ as, const float* __restrict__ ad,
    float* __restrict__ ss, float* __restrict__ sd, int n){
  int w = threadIdx.x >> 6, lane = threadIdx.x & 63;
  int row = blockIdx.x*4 + w;
  if (row >= n) return;
  const short* hr = hh + (size_t)row*192;
  float ps[3], pd[3];
  #pragma unroll
  for (int h=0; h<3; h++){
    float v = b2f(hr[h*64 + lane]);
    ps[h] = v * as[h*64+lane];
    pd[h] = v * ad[h*64+lane];
  }
  #pragma unroll
  for (int m=32; m; m>>=1){
    #pragma unroll
    for (int h=0;h<3;h++){ ps[h] += __shfl_xor(ps[h], m); pd[h] += __shfl_xor(pd[h], m); }
  }
  if (lane == 0){
    #pragma unroll
    for (int h=0;h<3;h++){ ss[row*3+h]=ps[h]; sd[row*3+h]=pd[h]; }
  }
}

__global__ __launch_bounds__(256) void gat1_gather_bf(const int* __restrict__ offs, const int* __restrict__ csr,
    const short* __restrict__ hh, const float* __restrict__ ss, const float* __restrict__ sd,
    const float* __restrict__ bias, short* __restrict__ out, int n){
  int w = threadIdx.x >> 6, lane = threadIdx.x & 63;
  int dst = blockIdx.x*4 + w;
  if (dst >= n) return;
  float sd0 = sd[dst*3+0], sd1 = sd[dst*3+1], sd2 = sd[dst*3+2];
  float p0 = __expf(lrelu(ss[dst*3+0]+sd0));
  float p1 = __expf(lrelu(ss[dst*3+1]+sd1));
  float p2 = __expf(lrelu(ss[dst*3+2]+sd2));
  const short* hr = hh + (size_t)dst*192;
  float a0 = p0*b2f(hr[lane]), a1 = p1*b2f(hr[64+lane]), a2 = p2*b2f(hr[128+lane]);
  float d0 = p0, d1 = p1, d2 = p2;
  int p = offs[dst], pe = offs[dst+1];
  for (; p+4 <= pe; p += 4){
    int s0=csr[p], s1=csr[p+1], s2=csr[p+2], s3=csr[p+3];
    float e00=ss[s0*3+0], e01=ss[s0*3+1], e02=ss[s0*3+2];
    float e10=ss[s1*3+0], e11=ss[s1*3+1], e12=ss[s1*3+2];
    float e20=ss[s2*3+0], e21=ss[s2*3+1], e22=ss[s2*3+2];
    float e30=ss[s3*3+0], e31=ss[s3*3+1], e32=ss[s3*3+2];
    const short* r0 = hh + (size_t)s0*192;
    const short* r1 = hh + (size_t)s1*192;
    const short* r2 = hh + (size_t)s2*192;
    const short* r3 = hh + (size_t)s3*192;
    float v00=b2f(r0[lane]), v01=b2f(r0[64+lane]), v02=b2f(r0[128+lane]);
    float v10=b2f(r1[lane]), v11=b2f(r1[64+lane]), v12=b2f(r1[128+lane]);
    float v20=b2f(r2[lane]), v21=b2f(r2[64+lane]), v22=b2f(r2[128+lane]);
    float v30=b2f(r3[lane]), v31=b2f(r3[64+lane]), v32=b2f(r3[128+lane]);
    float q00=__expf(lrelu(e00+sd0)), q01=__expf(lrelu(e01+sd1)), q02=__expf(lrelu(e02+sd2));
    float q10=__expf(lrelu(e10+sd0)), q11=__expf(lrelu(e11+sd1)), q12=__expf(lrelu(e12+sd2));
    float q20=__expf(lrelu(e20+sd0)), q21=__expf(lrelu(e21+sd1)), q22=__expf(lrelu(e22+sd2));
    float q30=__expf(lrelu(e30+sd0)), q31=__expf(lrelu(e31+sd1)), q32=__expf(lrelu(e32+sd2));
    a0 += q00*v00 + q10*v10 + q20*v20 + q30*v30;
    a1 += q01*v01 + q11*v11 + q21*v21 + q31*v31;
    a2 += q02*v02 + q12*v12 + q22*v22 + q32*v32;
    d0 += q00+q10+q20+q30;
    d1 += q01+q11+q21+q31;
    d2 += q02+q12+q22+q32;
  }
  for (; p < pe; ++p){
    int src = csr[p];
    float q0 = __expf(lrelu(ss[src*3+0]+sd0));
    float q1 = __expf(lrelu(ss[src*3+1]+sd1));
    float q2 = __expf(lrelu(ss[src*3+2]+sd2));
    const short* sr = hh + (size_t)src*192;
    a0 += q0*b2f(sr[lane]); a1 += q1*b2f(sr[64+lane]); a2 += q2*b2f(sr[128+lane]);
    d0 += q0; d1 += q1; d2 += q2;
  }
  float v0 = a0/d0 + bias[lane];
  float v1 = a1/d1 + bias[64+lane];
  float v2 = a2/d2 + bias[128+lane];
  short* orow = out + (size_t)dst*192;
  orow[lane]      = f2bf(v0 > 0.f ? v0 : 0.f);
  orow[64+lane]   = f2bf(v1 > 0.f ? v1 : 0.f);
  orow[128+lane]  = f2bf(v2 > 0.f ? v2 : 0.f);
}

// ==================== GAT2/3 fused (hh23 layout: [N][64], cols 0-29 = h2, 32-61 = h3) ====================
__global__ __launch_bounds__(256) void gat23_scores(const float* __restrict__ hh23,
    const float* __restrict__ a2s, const float* __restrict__ a2d,
    const float* __restrict__ a3s, const float* __restrict__ a3d,
    float* __restrict__ s2s, float* __restrict__ s2d, float* __restrict__ s3s, float* __restrict__ s3d, int n){
  int w = threadIdx.x >> 6, lane = threadIdx.x & 63;
  int row = blockIdx.x*4 + w;
  if (row >= n) return;
  float p[4] = {0.f,0.f,0.f,0.f};
  if (lane < 30){
    float v2 = hh23[(size_t)row*64+lane], v3 = hh23[(size_t)row*64+32+lane];
    p[0]=v2*a2s[lane]; p[1]=v2*a2d[lane]; p[2]=v3*a3s[lane]; p[3]=v3*a3d[lane];
  }
  #pragma unroll
  for (int m=32; m; m>>=1){
    #pragma unroll
    for (int j=0;j<4;j++) p[j] += __shfl_xor(p[j], m);
  }
  if (lane == 0){ s2s[row]=p[0]; s2d[row]=p[1]; s3s[row]=p[2]; s3d[row]=p[3]; }
}

__global__ __launch_bounds__(256) void gat23_gather(const int* __restrict__ offs, const int* __restrict__ csr,
    const float* __restrict__ hh23,
    const float* __restrict__ s2s, const float* __restrict__ s2d,
    const float* __restrict__ s3s, const float* __restrict__ s3d,
    const float* __restrict__ b2, const float* __restrict__ b3,
    float* __restrict__ zs, float* __restrict__ mus, float* __restrict__ lvs,
    short* __restrict__ zbf, int n){
  int w = threadIdx.x >> 6, lane = threadIdx.x & 63;
  int dst = blockIdx.x*4 + w;
  if (dst >= n) return;
  bool lo = lane < 32;
  int c = lane & 31;
  bool valid = c < 30;
  float sdA = s2d[dst], sdB = s3d[dst];
  float sdx = lo ? sdA : sdB;
  const float* ssx = lo ? s2s : s3s;
  float p2 = __expf(lrelu(s2s[dst]+sdA));
  float p3 = __expf(lrelu(s3s[dst]+sdB));
  float val = valid ? hh23[(size_t)dst*64+lane] : 0.f;
  float acc = (lo ? p2 : p3) * val;
  float den2 = p2, den3 = p3;
  int p = offs[dst], pe = offs[dst+1];
  for (; p+4 <= pe; p += 4){
    int s0=csr[p], s1=csr[p+1], s2i=csr[p+2], s3i=csr[p+3];
    float eA0=ssx[s0], eA1=ssx[s1], eA2=ssx[s2i], eA3=ssx[s3i];
    float f20=s2s[s0], f21=s2s[s1], f22=s2s[s2i], f23=s2s[s3i];
    float f30=s3s[s0], f31=s3s[s1], f32=s3s[s2i], f33=s3s[s3i];
    float v0 = valid ? hh23[(size_t)s0*64+lane] : 0.f;
    float v1 = valid ? hh23[(size_t)s1*64+lane] : 0.f;
    float v2 = valid ? hh23[(size_t)s2i*64+lane] : 0.f;
    float v3 = valid ? hh23[(size_t)s3i*64+lane] : 0.f;
    float qx0=__expf(lrelu(eA0+sdx)), qx1=__expf(lrelu(eA1+sdx));
    float qx2=__expf(lrelu(eA2+sdx)), qx3=__expf(lrelu(eA3+sdx));
    acc += qx0*v0 + qx1*v1 + qx2*v2 + qx3*v3;
    den2 += __expf(lrelu(f20+sdA)) + __expf(lrelu(f21+sdA)) + __expf(lrelu(f22+sdA)) + __expf(lrelu(f23+sdA));
    den3 += __expf(lrelu(f30+sdB)) + __expf(lrelu(f31+sdB)) + __expf(lrelu(f32+sdB)) + __expf(lrelu(f33+sdB));
  }
  for (; p < pe; ++p){
    int src = csr[p];
    float q2 = __expf(lrelu(s2s[src]+sdA));
    float q3 = __expf(lrelu(s3s[src]+sdB));
    float v = valid ? hh23[(size_t)src*64+lane] : 0.f;
    acc += (lo ? q2 : q3) * v;
    den2 += q2; den3 += q3;
  }
  if (lo){
    if (valid){
      float v = acc/den2 + b2[c];
      zs[(size_t)dst*30+c]  = v;
      mus[(size_t)dst*30+c] = v;
      zbf[(size_t)dst*32+c] = f2bf(v);
    } else {
      zbf[(size_t)dst*32+c] = 0;
    }
  } else if (valid){
    lvs[(size_t)dst*30+c] = acc/den3 + b3[c];
  }
}

// ==================== softmax ====================
__global__ __launch_bounds__(256) void softmax10(const float* __restrict__ in, float* __restrict__ out, int n){
  int row = blockIdx.x*256 + threadIdx.x;
  if (row >= n) return;
  const float* r = in + (size_t)row*10;
  float m = r[0];
  #pragma unroll
  for (int j=1;j<10;j++) m = fmaxf(m, r[j]);
  float e[10], s = 0.f;
  #pragma unroll
  for (int j=0;j<10;j++){ e[j] = __expf(r[j]-m); s += e[j]; }
  float inv = 1.f/s;
  float* o = out + (size_t)row*10;
  #pragma unroll
  for (int j=0;j<10;j++) o[j] = e[j]*inv;
}

// ==================== host ====================
static inline int cdiv(int a, int b){ return (a + b - 1) / b; }

extern "C" void kernel_launch(void* const* d_in, const int* in_sizes, int n_in,
                              void* d_out, int out_size, void* d_ws, size_t ws_size,
                              hipStream_t stream)
{
  const float* x        = (const float*)d_in[0];
  const int*   ei       = (const int*)  d_in[1];
  const float* enc_w1   = (const float*)d_in[2];
  const float* enc_g1   = (const float*)d_in[4];
  const float* enc_bt1  = (const float*)d_in[5];
  const float* enc_w2   = (const float*)d_in[6];
  const float* enc_g2   = (const float*)d_in[8];
  const float* enc_bt2  = (const float*)d_in[9];
  const float* gat1_w   = (const float*)d_in[10];
  const float* gat1_as  = (const float*)d_in[11];
  const float* gat1_ad  = (const float*)d_in[12];
  const float* gat1_b   = (const float*)d_in[13];
  const float* gat2_w   = (const float*)d_in[14];
  const float* gat2_as  = (const float*)d_in[15];
  const float* gat2_ad  = (const float*)d_in[16];
  const float* gat2_b   = (const float*)d_in[17];
  const float* gat3_w   = (const float*)d_in[18];
  const float* gat3_as  = (const float*)d_in[19];
  const float* gat3_ad  = (const float*)d_in[20];
  const float* gat3_b   = (const float*)d_in[21];
  const float* dec_w1   = (const float*)d_in[22];
  const float* dec_g1   = (const float*)d_in[24];
  const float* dec_bt1  = (const float*)d_in[25];
  const float* dec_w2   = (const float*)d_in[26];
  const float* dec_g2   = (const float*)d_in[28];
  const float* dec_bt2  = (const float*)d_in[29];
  const float* dec_w3   = (const float*)d_in[30];
  const float* dec_b3   = (const float*)d_in[31];
  const float* clu_w1   = (const float*)d_in[32];
  const float* clu_g1   = (const float*)d_in[34];
  const float* clu_bt1  = (const float*)d_in[35];
  const float* clu_w2   = (const float*)d_in[36];
  const float* clu_b2   = (const float*)d_in[37];

  const int N = in_sizes[0] / 1000;
  const int E = in_sizes[1] / 2;
  const int* e_src = ei;
  const int* e_dst = ei + E;
  const float invN = 1.f/(float)N;

  float* out  = (float*)d_out;
  float* pred = out;
  float* xrec = out + (size_t)N*10;
  float* zs   = xrec + (size_t)N*1000;
  float* mus  = zs  + (size_t)N*30;
  float* lvs  = mus + (size_t)N*30;

  char* ws = (char*)d_ws;
  size_t off = 0;
  auto alloc = [&](size_t bytes)->char*{
    char* p = ws + off;
    off = (off + bytes + 255) & ~(size_t)255;
    return p;
  };
  short* t_enc1  = (short*)alloc(256*1024*2);
  short* t_enc2  = (short*)alloc(128*256*2);
  short* t_gat1  = (short*)alloc(192*128*2);
  short* t_gat23 = (short*)alloc(64*192*2);
  short* t_dc1   = (short*)alloc(256*32*2);
  short* t_dec2  = (short*)alloc(256*128*2);
  short* t_dec3  = (short*)alloc(1024*256*2);
  short* t_clu2  = (short*)alloc(32*128*2);
  float* h1f  = (float*)alloc((size_t)N*256*4);
  short* h1b  = (short*)alloc((size_t)N*256*2);   // xb aliases from here
  float* h2f  = (float*)alloc((size_t)N*128*4);
  short* h2b  = (short*)alloc((size_t)N*128*2);
  short* hh1b = (short*)alloc((size_t)N*192*2);
  short* h3b  = (short*)alloc((size_t)N*192*2);
  float* hh23f= (float*)alloc((size_t)N*64*4);
  short* zbf  = (short*)alloc((size_t)N*32*2);
  float* ss1  = (float*)alloc((size_t)N*3*4);
  float* sd1  = (float*)alloc((size_t)N*3*4);
  float* s2s  = (float*)alloc((size_t)N*4);
  float* s2d  = (float*)alloc((size_t)N*4);
  float* s3s  = (float*)alloc((size_t)N*4);
  float* s3d  = (float*)alloc((size_t)N*4);
  float* stats= (float*)alloc(2048*4);
  int*   deg  = (int*)alloc((size_t)(N+1)*4);
  int*   offs = (int*)alloc((size_t)(N+1)*4);
  int*   curp = (int*)alloc((size_t)(N+1)*4);
  int*   bsum = (int*)alloc(256*4);
  int*   csr  = (int*)alloc((size_t)E*4);
  // aliases (lifetimes verified):
  short* xb   = h1b;                               // spans h1b..h3b (102.4MB >= 100MB+pad); dead after enc1 gemm
  float* dc1f = h2f;                               // [N][256] f32 spans h2f+h2b+hh1b (57.6MB); after gat1_gather
  short* d1b  = h3b;                               // after gat23 gemm
  short* c1b  = (short*)hh23f;                     // after gat23 gather
  float* d2f  = h1f;                               // after enc1 apply
  short* d2b  = h1b;                               // after enc2 gemm (xb also dead)
  float* c2   = (float*)zbf;                       // [N][10] f32 (2MB < 3.2MB); zbf dead after dc1 gemm
  // stats layout: enc1 sum@0 sq@256 | enc2 sum@512 sq@640 | dc1 sum@768 sq@1024 | dec2 sum@1280 sq@1536
  float* st_enc1 = stats, *st_enc2 = stats+512, *st_dc1 = stats+768, *st_dec2 = stats+1280;

  // --- weight prep + upfront zeroing ---
  WTab tab;
  tab.e[0] = {enc_w1, t_enc1, 1000, 256, 1024, 256};
  tab.e[1] = {enc_w2, t_enc2, 256, 128, 256, 128};
  tab.e[2] = {gat1_w, t_gat1, 128, 192, 128, 192};
  tab.e[3] = {gat2_w, t_gat23, 192, 30, 192, 32};
  tab.e[4] = {gat3_w, t_gat23 + 32*192, 192, 30, 192, 32};
  tab.e[5] = {dec_w1, t_dc1, 30, 128, 32, 128};
  tab.e[6] = {clu_w1, t_dc1 + 128*32, 30, 128, 32, 128};
  tab.e[7] = {dec_w2, t_dec2, 128, 256, 128, 256};
  tab.e[8] = {dec_w3, t_dec3, 256, 1000, 256, 1024};
  tab.e[9] = {clu_w2, t_clu2, 128, 10, 128, 32};
  wtrans_all<<<dim3(1024, 10), 256, 0, stream>>>(tab);
  hipMemsetAsync(stats, 0, 2048*4, stream);
  hipMemsetAsync(deg, 0, (size_t)(N+1)*4, stream);

  // --- CSR ---
  hist_kernel<<<cdiv(E,256), 256, 0, stream>>>(e_dst, E, deg);
  int nb = cdiv(N, 1024);
  scan1<<<nb, 256, 0, stream>>>(deg, offs, bsum, N);
  scan3<<<cdiv(N,256), 256, 0, stream>>>(offs, bsum, curp, N, E);
  scatter_kernel<<<cdiv(E,256), 256, 0, stream>>>(e_src, e_dst, E, curp, csr);

  const int MB = cdiv(N, 128);

  // --- encoder L1: cvt to bf16, then BW-bound GEMM ---
  cvt_x<<<cdiv(N,2), 256, 0, stream>>>(x, xb, N);
  gemm_g<128,false,true><<<dim3(MB,2), 256, 0, stream>>>(xb, 1000, t_enc1, 1024, h1f, nullptr, st_enc1, st_enc1+256, N, 256, 1000, 256);
  bn_elu_apply2<256><<<2048, 256, 0, stream>>>(h1f, h1b, N, invN, st_enc1, st_enc1+256, enc_g1, enc_bt1);

  // --- encoder L2 ---
  gemm_g<128,false,true><<<dim3(MB,1), 256, 0, stream>>>(h1b, 256, t_enc2, 256, h2f, nullptr, st_enc2, st_enc2+128, N, 128, 256, 128);
  bn_elu_apply2<128><<<2048, 256, 0, stream>>>(h2f, h2b, N, invN, st_enc2, st_enc2+128, enc_g2, enc_bt2);

  // --- GAT1 ---
  gemm_g<64,true,false><<<dim3(MB,3), 256, 0, stream>>>(h2b, 128, t_gat1, 128, hh1b, nullptr, nullptr, nullptr, N, 192, 128, 192);
  gat1_scores_bf<<<cdiv(N,4), 256, 0, stream>>>(hh1b, gat1_as, gat1_ad, ss1, sd1, N);
  gat1_gather_bf<<<cdiv(N,4), 256, 0, stream>>>(offs, csr, hh1b, ss1, sd1, gat1_b, h3b, N);

  // --- GAT2+GAT3 (combined weights) ---
  gemm_g<64,false,false><<<dim3(MB,1), 256, 0, stream>>>(h3b, 192, t_gat23, 192, hh23f, nullptr, nullptr, nullptr, N, 64, 192, 64);
  gat23_scores<<<cdiv(N,4), 256, 0, stream>>>(hh23f, gat2_as, gat2_ad, gat3_as, gat3_ad, s2s, s2d, s3s, s3d, N);
  gat23_gather<<<cdiv(N,4), 256, 0, stream>>>(offs, csr, hh23f, s2s, s2d, s3s, s3d, gat2_b, gat3_b, zs, mus, lvs, zbf, N);

  // --- dec1 + clu1 combined ---
  gemm_g<128,false,true><<<dim3(MB,2), 256, 0, stream>>>(zbf, 32, t_dc1, 32, dc1f, nullptr, st_dc1, st_dc1+256, N, 256, 32, 256);
  bn_elu_split<<<2048, 256, 0, stream>>>(dc1f, d1b, c1b, N, invN, st_dc1, st_dc1+256, dec_g1, dec_bt1, clu_g1, clu_bt1);

  // --- dec2 ---
  gemm_g<128,false,true><<<dim3(MB,2), 256, 0, stream>>>(d1b, 128, t_dec2, 128, d2f, nullptr, st_dec2, st_dec2+256, N, 256, 128, 256);
  bn_elu_apply2<256><<<2048, 256, 0, stream>>>(d2f, d2b, N, invN, st_dec2, st_dec2+256, dec_g2, dec_bt2);

  // --- dec3 ---
  gemm_g<128,false,false><<<dim3(MB,8), 256, 0, stream>>>(d2b, 256, t_dec3, 256, xrec, dec_b3, nullptr, nullptr, N, 1000, 256, 1000);

  // --- clu2 + softmax ---
  gemm_g<32,false,false><<<dim3(MB,1), 256, 0, stream>>>(c1b, 128, t_clu2, 128, c2, clu_b2, nullptr, nullptr, N, 10, 128, 10);
  softmax10<<<cdiv(N,256), 256, 0, stream>>>(c2, pred, N);
}